// Round 12
// baseline (539.039 us; speedup 1.0000x reference)
//
#include <hip/hip_runtime.h>
#include <math.h>

typedef unsigned short u16;
typedef short short8 __attribute__((ext_vector_type(8)));
typedef float f32x4 __attribute__((ext_vector_type(4)));

#define TT 4
#define BB 4096
#define DIM 512
#define HDIM 1024
#define BD (BB*DIM)      // 2097152
#define BH (BB*HDIM)     // 4194304
#define D2 (DIM*DIM)     // 262144
#define NEXP 20

#define GLOAD16(gp, lp) __builtin_amdgcn_global_load_lds( \
    (__attribute__((address_space(1))) void*)(void*)(gp), \
    (__attribute__((address_space(3))) void*)(void*)(lp), 16, 0, 0)

__device__ __forceinline__ u16 f2b(float f) {
  union { float f; unsigned u; } x; x.f = f;
  unsigned r = x.u + 0x7FFFu + ((x.u >> 16) & 1u);
  return (u16)(r >> 16);
}
__device__ __forceinline__ float b2f(u16 v) {
  union { unsigned u; float f; } x; x.u = ((unsigned)v) << 16; return x.f;
}

__device__ __forceinline__ float wsum(float v) {
#pragma unroll
  for (int o = 32; o > 0; o >>= 1) v += __shfl_xor(v, o);
  return v;
}

// fast exact-enough GELU
__device__ __forceinline__ float fgelu(float v) {
  float u = 1.5957691216057308f * v * (1.0f + 0.044715f * v * v);
  return v / (1.0f + __expf(-u));
}

// ------ prep: one wave per row b: mean, bf16 casts, score-bias sbias --------
__global__ __launch_bounds__(256) void k_prep(const float* __restrict__ ti,
                                              const float* __restrict__ qwkb,
                                              const float* __restrict__ kbqb,
                                              u16* __restrict__ tib,
                                              u16* __restrict__ xsb,
                                              float* __restrict__ sbias) {
  int gw = (blockIdx.x * 256 + threadIdx.x) >> 6;   // row b
  int lane = threadIdx.x & 63;
  int d0 = lane * 8;
  float x[4][8];
#pragma unroll
  for (int t = 0; t < 4; t++) {
    const float* p = ti + ((size_t)t * BB + gw) * DIM + d0;
    *(float4*)&x[t][0] = *(const float4*)p;
    *(float4*)&x[t][4] = *(const float4*)(p + 4);
  }
  float m[8];
#pragma unroll
  for (int j = 0; j < 8; j++)
    m[j] = (x[0][j] + x[1][j] + x[2][j] + x[3][j]) * 0.25f;
#pragma unroll
  for (int t = 0; t < 4; t++) {
    ushort4 c0 = { f2b(x[t][0]), f2b(x[t][1]), f2b(x[t][2]), f2b(x[t][3]) };
    ushort4 c1 = { f2b(x[t][4]), f2b(x[t][5]), f2b(x[t][6]), f2b(x[t][7]) };
    u16* q = tib + ((size_t)t * BB + gw) * DIM + d0;
    *(ushort4*)q = c0; *(ushort4*)(q + 4) = c1;
  }
  {
    ushort4 c0 = { f2b(m[0]), f2b(m[1]), f2b(m[2]), f2b(m[3]) };
    ushort4 c1 = { f2b(m[4]), f2b(m[5]), f2b(m[6]), f2b(m[7]) };
    u16* q = xsb + (size_t)gw * DIM + d0;
    *(ushort4*)q = c0; *(ushort4*)(q + 4) = c1;
  }
#pragma unroll
  for (int t = 0; t < 4; t++) {
    const float* wp = qwkb + (size_t)t * DIM + d0;
    float4 w0 = *(const float4*)wp, w1 = *(const float4*)(wp + 4);
    float s = x[t][0]*w0.x + x[t][1]*w0.y + x[t][2]*w0.z + x[t][3]*w0.w
            + x[t][4]*w1.x + x[t][5]*w1.y + x[t][6]*w1.z + x[t][7]*w1.w;
    s = wsum(s);
    if (lane == 0) sbias[(size_t)t * BB + gw] = s + kbqb[t];
  }
}

// ------------- batched transpose+cast: (G,R,C) f32 -> (G,C,R) bf16 -----------
__global__ __launch_bounds__(256) void k_tcast(const float* __restrict__ in,
                                               u16* __restrict__ out,
                                               int R, int C) {
  __shared__ float tile[32][33];
  size_t gb = (size_t)blockIdx.z * R * C;
  in += gb; out += gb;
  int c0 = blockIdx.x * 32, r0 = blockIdx.y * 32;
  int tx = threadIdx.x & 31, ty = threadIdx.x >> 5;
#pragma unroll
  for (int j = 0; j < 4; j++)
    tile[ty + j * 8][tx] = in[(size_t)(r0 + ty + j * 8) * C + c0 + tx];
  __syncthreads();
#pragma unroll
  for (int j = 0; j < 4; j++)
    out[(size_t)(c0 + ty + j * 8) * R + r0 + tx] = f2b(tile[tx][ty + j * 8]);
}

// ---------------- plain cast f32 -> bf16 -------------------------------------
__global__ __launch_bounds__(256) void k_cast(const float* __restrict__ in,
                                              u16* __restrict__ out) {
  size_t i = ((size_t)blockIdx.x * 256 + threadIdx.x) * 4;
  float4 v = *(const float4*)(in + i);
  ushort4 b = { f2b(v.x), f2b(v.y), f2b(v.z), f2b(v.w) };
  *(ushort4*)(out + i) = b;
}

// --------------- small bias-vector precomputes -------------------------------
__global__ __launch_bounds__(256) void k_biasvec(const float* __restrict__ qw,
                                                 const float* __restrict__ kb,
                                                 const float* __restrict__ kw,
                                                 const float* __restrict__ qb,
                                                 float* __restrict__ qwkb,
                                                 float* __restrict__ kwqb,
                                                 float* __restrict__ kbqb) {
  int gw = (blockIdx.x * 256 + threadIdx.x) >> 6;
  int lane = threadIdx.x & 63;
  if (gw < 2048) {
    int t = gw >> 9, c = gw & 511;
    const float* row = qw + ((size_t)t * DIM + c) * DIM;
    const float* v = kb + (size_t)t * DIM;
    float s = 0;
#pragma unroll
    for (int j = 0; j < 8; j++) s += row[lane * 8 + j] * v[lane * 8 + j];
    s = wsum(s);
    if (lane == 0) qwkb[(size_t)t * DIM + c] = s;
  } else if (gw < 4096) {
    int t = (gw - 2048) >> 9, d = gw & 511;
    const float* row = kw + ((size_t)t * DIM + d) * DIM;
    const float* v = qb + (size_t)t * DIM;
    float s = 0;
#pragma unroll
    for (int j = 0; j < 8; j++) s += row[lane * 8 + j] * v[lane * 8 + j];
    s = wsum(s);
    if (lane == 0) kwqb[(size_t)t * DIM + d] = s;
  } else if (gw < 4100) {
    int t = gw - 4096;
    const float* a = kb + (size_t)t * DIM;
    const float* c = qb + (size_t)t * DIM;
    float s = 0;
#pragma unroll
    for (int j = 0; j < 8; j++) s += a[lane * 8 + j] * c[lane * 8 + j];
    s = wsum(s);
    if (lane == 0) kbqb[t] = s;
  }
}

// ------- 128x128 bf16 MFMA GEMM mainloop (NT), single-buffer BK=64 -----------
// 32 KB burst per step; swizzle: LDS[row][p] = global chunk (p ^ (row&7)).
__device__ __forceinline__ void gemm128(const u16* __restrict__ Ag, int lda,
                                        const u16* __restrict__ Bg, int ldb,
                                        int K, f32x4 acc[4][4], bool swapped) {
  __shared__ __align__(16) u16 lA[8192];   // 128 x 64
  __shared__ __align__(16) u16 lB[8192];
  const int tid = threadIdx.x;
  const int lane = tid & 63;
  const int wave = tid >> 6;
  const int wm = wave >> 1, wn = wave & 1;
  const int rl = lane & 15;
  const int q = lane >> 4;            // 0..3
  const int s = rl & 7;
  const u16* aP[4]; const u16* bP[4];
#pragma unroll
  for (int i = 0; i < 4; i++) {
    int c16 = tid + 256 * i;
    int row = c16 >> 3;
    int gch = (c16 & 7) ^ (row & 7);  // pre-swizzled global chunk
    aP[i] = Ag + (size_t)row * lda + gch * 8;
    bP[i] = Bg + (size_t)row * ldb + gch * 8;
  }
  const int arow = (wm * 64 + rl) * 64;
  const int brow = (wn * 64 + rl) * 64;
  const int ch0 = (q ^ s) * 8;        // ks=0
  const int ch1 = ((4 + q) ^ s) * 8;  // ks=1
  const int nsteps = K >> 6;
  for (int k = 0; k < nsteps; ++k) {
    const int off = k * 64;
    __syncthreads();
#pragma unroll
    for (int i = 0; i < 4; i++) {
      GLOAD16(aP[i] + off, &lA[(tid + 256 * i) * 8]);
      GLOAD16(bP[i] + off, &lB[(tid + 256 * i) * 8]);
    }
    __syncthreads();
#pragma unroll
    for (int ks = 0; ks < 2; ks++) {
      const int co = ks ? ch1 : ch0;
      short8 af[4], bf[4];
#pragma unroll
      for (int i = 0; i < 4; i++) {
        af[i] = *(const short8*)&lA[arow + i * 1024 + co];
        bf[i] = *(const short8*)&lB[brow + i * 1024 + co];
      }
      __builtin_amdgcn_s_setprio(1);
      if (swapped) {
#pragma unroll
        for (int mi = 0; mi < 4; mi++)
#pragma unroll
          for (int ni = 0; ni < 4; ni++)
            acc[mi][ni] = __builtin_amdgcn_mfma_f32_16x16x32_bf16(bf[ni], af[mi],
                                                                  acc[mi][ni], 0, 0, 0);
      } else {
#pragma unroll
        for (int mi = 0; mi < 4; mi++)
#pragma unroll
          for (int ni = 0; ni < 4; ni++)
            acc[mi][ni] = __builtin_amdgcn_mfma_f32_16x16x32_bf16(af[mi], bf[ni],
                                                                  acc[mi][ni], 0, 0, 0);
      }
      __builtin_amdgcn_s_setprio(0);
    }
  }
}

// ---------------- expert up-GEMM: h = gelu(x@W1 + b1), bf16 out --------------
// swapped layout: lane owns (row=rl, 4 consecutive cols) -> ushort4 stores.
__global__ __launch_bounds__(256) void k_gemm_up(const u16* __restrict__ xsb,
                                                 const u16* __restrict__ tib,
                                                 const u16* __restrict__ w1t,
                                                 const float* __restrict__ sb1,
                                                 const float* __restrict__ tb1,
                                                 u16* __restrict__ hbuf,
                                                 int row0, int SR) {
  int ge = blockIdx.z;
  const u16* A;
  const float* bias;
  if (ge < 4) { A = xsb; bias = sb1 + (size_t)ge * HDIM; }
  else {
    int te = ge - 4;
    A = tib + (size_t)(te >> 2) * BD;
    bias = tb1 + (size_t)te * HDIM;
  }
  A += (size_t)row0 * DIM;
  const u16* W = w1t + (size_t)ge * ((size_t)HDIM * DIM);
  int m0 = blockIdx.y * 128, n0 = blockIdx.x * 128;
  f32x4 acc[4][4] = {};
  gemm128(A + (size_t)m0 * DIM, DIM, W + (size_t)n0 * DIM, DIM, DIM, acc, true);
  u16* out = hbuf + (size_t)ge * ((size_t)SR * HDIM);
  const int lane = threadIdx.x & 63, wave = threadIdx.x >> 6;
  const int rl = lane & 15, c4 = (lane >> 4) * 4;
  const int wm = wave >> 1, wn = wave & 1;
#pragma unroll
  for (int mf = 0; mf < 4; mf++) {
    int row = m0 + wm * 64 + mf * 16 + rl;
#pragma unroll
    for (int nf = 0; nf < 4; nf++) {
      int col0 = n0 + wn * 64 + nf * 16 + c4;
      float4 bb = *(const float4*)(bias + col0);
      ushort4 y;
      y.x = f2b(fgelu(acc[mf][nf][0] + bb.x));
      y.y = f2b(fgelu(acc[mf][nf][1] + bb.y));
      y.z = f2b(fgelu(acc[mf][nf][2] + bb.z));
      y.w = f2b(fgelu(acc[mf][nf][3] + bb.w));
      *(ushort4*)(out + (size_t)row * HDIM + col0) = y;
    }
  }
}

// ---- down-GEMM: preLN bf16 = h@W2 + b2 + residual -> stk16[20][B][D] --------
__global__ __launch_bounds__(256) void k_gemm_down(const u16* __restrict__ hbuf,
                                                   const u16* __restrict__ w2t,
                                                   const float* __restrict__ sb2,
                                                   const float* __restrict__ tb2,
                                                   const u16* __restrict__ xsb,
                                                   const u16* __restrict__ tib,
                                                   u16* __restrict__ stk16,
                                                   int row0, int SR) {
  int ge = blockIdx.z;
  int m0 = blockIdx.y * 128, n0 = blockIdx.x * 128;
  const u16* Ag = hbuf + (size_t)ge * ((size_t)SR * HDIM) + (size_t)m0 * HDIM;
  const u16* Bg = w2t + (size_t)ge * ((size_t)DIM * HDIM) + (size_t)n0 * HDIM;
  f32x4 acc[4][4] = {};
  gemm128(Ag, HDIM, Bg, HDIM, HDIM, acc, true);
  const float* bias; const u16* resb;
  int te = ge - 4;
  if (ge < 4) { bias = sb2 + (size_t)ge * DIM; resb = xsb; }
  else { bias = tb2 + (size_t)te * DIM; resb = tib + (size_t)(te >> 2) * BD; }
  const int lane = threadIdx.x & 63, wave = threadIdx.x >> 6;
  const int rl = lane & 15, c4 = (lane >> 4) * 4;
  const int wm = wave >> 1, wn = wave & 1;
  u16* outb = stk16 + (size_t)ge * BD;
#pragma unroll
  for (int mf = 0; mf < 4; mf++) {
    int grow = row0 + m0 + wm * 64 + mf * 16 + rl;
#pragma unroll
    for (int nf = 0; nf < 4; nf++) {
      int col0 = n0 + wn * 64 + nf * 16 + c4;
      float4 bb = *(const float4*)(bias + col0);
      ushort4 rr = *(const ushort4*)(resb + (size_t)grow * DIM + col0);
      ushort4 y;
      y.x = f2b(acc[mf][nf][0] + bb.x + b2f(rr.x));
      y.y = f2b(acc[mf][nf][1] + bb.y + b2f(rr.y));
      y.z = f2b(acc[mf][nf][2] + bb.z + b2f(rr.z));
      y.w = f2b(acc[mf][nf][3] + bb.w + b2f(rr.w));
      *(ushort4*)(outb + (size_t)grow * DIM + col0) = y;
    }
  }
}

// ---------------- MT[t] = kw[t] @ qw[t]^T  (bf16 out) ------------------------
__global__ __launch_bounds__(256) void k_gemm_mt(const u16* __restrict__ kwb,
                                                 const u16* __restrict__ qwb,
                                                 u16* __restrict__ mt) {
  int t = blockIdx.z;
  int m0 = blockIdx.y * 128, n0 = blockIdx.x * 128;
  f32x4 acc[4][4] = {};
  gemm128(kwb + (size_t)t * D2 + (size_t)m0 * DIM, DIM,
          qwb + (size_t)t * D2 + (size_t)n0 * DIM, DIM, DIM, acc, true);
  const int lane = threadIdx.x & 63, wave = threadIdx.x >> 6;
  const int rl = lane & 15, c4 = (lane >> 4) * 4;
  const int wm = wave >> 1, wn = wave & 1;
#pragma unroll
  for (int mf = 0; mf < 4; mf++) {
    int row = m0 + wm * 64 + mf * 16 + rl;
#pragma unroll
    for (int nf = 0; nf < 4; nf++) {
      int col0 = n0 + wn * 64 + nf * 16 + c4;
      ushort4 y = { f2b(acc[mf][nf][0]), f2b(acc[mf][nf][1]),
                    f2b(acc[mf][nf][2]), f2b(acc[mf][nf][3]) };
      *(ushort4*)(mt + (size_t)t * D2 + (size_t)row * DIM + col0) = y;
    }
  }
}

// ------------- qkb[t] = bf16(x[t] @ MT[t]^T + kwqb[t]) -----------------------
__global__ __launch_bounds__(256) void k_gemm_qk(const u16* __restrict__ tib,
                                                 const u16* __restrict__ mt,
                                                 const float* __restrict__ kwqb,
                                                 u16* __restrict__ qkb) {
  int t = blockIdx.z;
  int m0 = blockIdx.y * 128, n0 = blockIdx.x * 128;
  f32x4 acc[4][4] = {};
  gemm128(tib + (size_t)t * BD + (size_t)m0 * DIM, DIM,
          mt + (size_t)t * D2 + (size_t)n0 * DIM, DIM, DIM, acc, true);
  const int lane = threadIdx.x & 63, wave = threadIdx.x >> 6;
  const int rl = lane & 15, c4 = (lane >> 4) * 4;
  const int wm = wave >> 1, wn = wave & 1;
#pragma unroll
  for (int mf = 0; mf < 4; mf++) {
    int row = m0 + wm * 64 + mf * 16 + rl;
#pragma unroll
    for (int nf = 0; nf < 4; nf++) {
      int col0 = n0 + wn * 64 + nf * 16 + c4;
      float4 bb = *(const float4*)(kwqb + (size_t)t * DIM + col0);
      ushort4 y;
      y.x = f2b(acc[mf][nf][0] + bb.x);
      y.y = f2b(acc[mf][nf][1] + bb.y);
      y.z = f2b(acc[mf][nf][2] + bb.z);
      y.w = f2b(acc[mf][nf][3] + bb.w);
      *(ushort4*)(qkb + (size_t)t * BD + (size_t)row * DIM + col0) = y;
    }
  }
}

// ---- fused LN + scores + softmax + gating (one wave per (t,b)) --------------
__global__ __launch_bounds__(256) void k_score(const u16* __restrict__ stk16,
                                               const u16* __restrict__ qkb,
                                               const float* __restrict__ sbias,
                                               const float* __restrict__ sg,
                                               const float* __restrict__ sbt,
                                               const float* __restrict__ tg,
                                               const float* __restrict__ tbt,
                                               float* __restrict__ stacked,
                                               float* __restrict__ gated,
                                               float* __restrict__ wout) {
  int gw = (blockIdx.x * 256 + threadIdx.x) >> 6;
  int lane = threadIdx.x & 63;
  int b = gw & (BB - 1), t = gw >> 12;
  int d0 = lane * 8;
  size_t rowoff = ((size_t)t * BB + b) * DIM + d0;
  float qr[8];
  {
    ushort4 q0 = *(const ushort4*)(qkb + rowoff);
    ushort4 q1 = *(const ushort4*)(qkb + rowoff + 4);
    qr[0] = b2f(q0.x); qr[1] = b2f(q0.y); qr[2] = b2f(q0.z); qr[3] = b2f(q0.w);
    qr[4] = b2f(q1.x); qr[5] = b2f(q1.y); qr[6] = b2f(q1.z); qr[7] = b2f(q1.w);
  }
  float stv[8][8];
  float dots[8];
#pragma unroll
  for (int n = 0; n < 8; n++) {
    int e = (n < 4) ? n : (4 + t * 4 + (n - 4));
    const u16* sp = stk16 + ((size_t)e * BB + b) * DIM + d0;
    ushort4 v0 = *(const ushort4*)sp;
    ushort4 v1 = *(const ushort4*)(sp + 4);
    float v[8] = { b2f(v0.x), b2f(v0.y), b2f(v0.z), b2f(v0.w),
                   b2f(v1.x), b2f(v1.y), b2f(v1.z), b2f(v1.w) };
    float S = 0, Q = 0;
#pragma unroll
    for (int j = 0; j < 8; j++) { S += v[j]; Q += v[j] * v[j]; }
    S = wsum(S); Q = wsum(Q);
    float mu = S * (1.0f / DIM);
    float var = Q * (1.0f / DIM) - mu * mu;
    float rs = rsqrtf(var + 1e-5f);
    const float* gp; const float* bp;
    if (n < 4) { gp = sg + (size_t)n * DIM; bp = sbt + (size_t)n * DIM; }
    else {
      int te = t * 4 + (n - 4);
      gp = tg + (size_t)te * DIM; bp = tbt + (size_t)te * DIM;
    }
    float4 g0 = *(const float4*)(gp + d0), g1 = *(const float4*)(gp + d0 + 4);
    float4 b0 = *(const float4*)(bp + d0), b1 = *(const float4*)(bp + d0 + 4);
    float gv[8] = { g0.x, g0.y, g0.z, g0.w, g1.x, g1.y, g1.z, g1.w };
    float bv[8] = { b0.x, b0.y, b0.z, b0.w, b1.x, b1.y, b1.z, b1.w };
    float dd = 0;
#pragma unroll
    for (int j = 0; j < 8; j++) {
      float y = (v[j] - mu) * rs * gv[j] + bv[j];
      stv[n][j] = y;
      dd += y * qr[j];
    }
    float* so = stacked + (((size_t)t * 8 + n) * BB + b) * DIM + d0;
    *(float4*)so = *(float4*)&stv[n][0];
    *(float4*)(so + 4) = *(float4*)&stv[n][4];
    dots[n] = wsum(dd);
  }
  float sb = sbias[(size_t)t * BB + b];
  const float inv = 0.04419417382415922f;  // 1/sqrt(512)
  float sc[8], e[8];
  float mx = -1e30f;
#pragma unroll
  for (int n = 0; n < 8; n++) { sc[n] = (dots[n] + sb) * inv; mx = fmaxf(mx, sc[n]); }
  float den = 0;
#pragma unroll
  for (int n = 0; n < 8; n++) { e[n] = expf(sc[n] - mx); den += e[n]; }
  float rden = 1.0f / den;
  float wv[8];
#pragma unroll
  for (int n = 0; n < 8; n++) wv[n] = e[n] * rden;
  float wsel = 0;
#pragma unroll
  for (int n = 0; n < 8; n++) wsel = (lane == n) ? wv[n] : wsel;
  if (lane < 8) wout[((size_t)t * BB + b) * 8 + lane] = wsel;
  float g[8];
#pragma unroll
  for (int j = 0; j < 8; j++) {
    float s = 0;
#pragma unroll
    for (int n = 0; n < 8; n++) s += wv[n] * stv[n][j];
    g[j] = s;
  }
  float* go = gated + rowoff;
  *(float4*)(go) = *(float4*)&g[0];
  *(float4*)(go + 4) = *(float4*)&g[4];
}

// ============================ host launcher ==================================
extern "C" void kernel_launch(void* const* d_in, const int* in_sizes, int n_in,
                              void* d_out, int out_size, void* d_ws, size_t ws_size,
                              hipStream_t stream) {
  const float* ti  = (const float*)d_in[0];
  const float* sw1 = (const float*)d_in[1];
  const float* sb1 = (const float*)d_in[2];
  const float* sw2 = (const float*)d_in[3];
  const float* sb2 = (const float*)d_in[4];
  const float* sg  = (const float*)d_in[5];
  const float* sbt = (const float*)d_in[6];
  const float* tw1 = (const float*)d_in[7];
  const float* tb1 = (const float*)d_in[8];
  const float* tw2 = (const float*)d_in[9];
  const float* tb2 = (const float*)d_in[10];
  const float* tg  = (const float*)d_in[11];
  const float* tbt = (const float*)d_in[12];
  const float* qw  = (const float*)d_in[13];
  const float* qb  = (const float*)d_in[14];
  const float* kw  = (const float*)d_in[15];
  const float* kb  = (const float*)d_in[16];

  float* out = (float*)d_out;
  float* gated   = out;                                   // T*B*D
  float* weights = out + (size_t)TT * BB * DIM;           // T*B*8
  float* stacked = weights + (size_t)TT * BB * 8;         // T*8*B*D

  char* ws = (char*)d_ws;
  u16*   tib   = (u16*)(ws);                    // 16,777,216
  u16*   xsb   = (u16*)(ws + 16777216);         //  4,194,304
  u16*   w1t   = (u16*)(ws + 20971520);         // 20,971,520
  u16*   w2t   = (u16*)(ws + 41943040);         // 20,971,520
  u16*   qwb   = (u16*)(ws + 62914560);         //  2,097,152
  u16*   kwb   = (u16*)(ws + 65011712);         //  2,097,152
  u16*   mt    = (u16*)(ws + 67108864);         //  2,097,152
  float* sbias = (float*)(ws + 69206016);       //     65,536
  float* qwkb  = (float*)(ws + 69271552);       //      8,192
  float* kwqb  = (float*)(ws + 69279744);       //      8,192
  float* kbqb  = (float*)(ws + 69287936);       //      1,024
  u16*   qkb   = (u16*)(ws + 69288960);         // 16,777,216
  u16*   stk16 = (u16*)(ws + 86066176);         // 83,886,080 (20*B*D bf16)
  u16*   hbuf  = (u16*)(ws + 169952256);        // SR*HDIM*2*20

  const size_t hoff = 169952256;
  int SR = 512;
  if (ws_size >= hoff + (size_t)NEXP * BB * HDIM * 2) SR = BB;           // 338 MB
  else if (ws_size >= hoff + (size_t)NEXP * 1024 * HDIM * 2) SR = 1024;

  // weight / gate preprocessing
  k_tcast<<<dim3(32, 16, 4), 256, 0, stream>>>(sw1, w1t, DIM, HDIM);
  k_tcast<<<dim3(32, 16, 16), 256, 0, stream>>>(tw1, w1t + (size_t)4 * HDIM * DIM, DIM, HDIM);
  k_tcast<<<dim3(16, 32, 4), 256, 0, stream>>>(sw2, w2t, HDIM, DIM);
  k_tcast<<<dim3(16, 32, 16), 256, 0, stream>>>(tw2, w2t + (size_t)4 * DIM * HDIM, HDIM, DIM);
  k_cast<<<1024, 256, 0, stream>>>(qw, qwb);
  k_cast<<<1024, 256, 0, stream>>>(kw, kwb);
  k_biasvec<<<1025, 256, 0, stream>>>(qw, kb, kw, qb, qwkb, kwqb, kbqb);
  k_prep<<<1024, 256, 0, stream>>>(ti, qwkb, kbqb, tib, xsb, sbias);
  k_gemm_mt<<<dim3(4, 4, 4), 256, 0, stream>>>(kwb, qwb, mt);

  // expert FFNs: both GEMMs 128x128-tile, BK=64 single-buffer, high-TLP grids
  for (int row0 = 0; row0 < BB; row0 += SR) {
    k_gemm_up<<<dim3(8, SR / 128, NEXP), 256, 0, stream>>>(xsb, tib, w1t, sb1, tb1,
                                                           hbuf, row0, SR);
    k_gemm_down<<<dim3(4, SR / 128, NEXP), 256, 0, stream>>>(hbuf, w2t, sb2, tb2,
                                                             xsb, tib, stk16, row0, SR);
  }

  k_gemm_qk<<<dim3(4, 32, 4), 256, 0, stream>>>(tib, mt, kwqb, qkb);
  k_score<<<4096, 256, 0, stream>>>(stk16, qkb, sbias, sg, sbt, tg, tbt,
                                    stacked, gated, weights);
}

// Round 13
// 537.334 us; speedup vs baseline: 1.0032x; 1.0032x over previous
//
#include <hip/hip_runtime.h>
#include <math.h>

typedef unsigned short u16;
typedef short short8 __attribute__((ext_vector_type(8)));
typedef float f32x4 __attribute__((ext_vector_type(4)));

#define TT 4
#define BB 4096
#define DIM 512
#define HDIM 1024
#define BD (BB*DIM)      // 2097152
#define BH (BB*HDIM)     // 4194304
#define D2 (DIM*DIM)     // 262144
#define NEXP 20

#define GLOAD16(gp, lp) __builtin_amdgcn_global_load_lds( \
    (__attribute__((address_space(1))) void*)(void*)(gp), \
    (__attribute__((address_space(3))) void*)(void*)(lp), 16, 0, 0)

__device__ __forceinline__ u16 f2b(float f) {
  union { float f; unsigned u; } x; x.f = f;
  unsigned r = x.u + 0x7FFFu + ((x.u >> 16) & 1u);
  return (u16)(r >> 16);
}
__device__ __forceinline__ float b2f(u16 v) {
  union { unsigned u; float f; } x; x.u = ((unsigned)v) << 16; return x.f;
}

__device__ __forceinline__ float wsum(float v) {
#pragma unroll
  for (int o = 32; o > 0; o >>= 1) v += __shfl_xor(v, o);
  return v;
}

// fast exact-enough GELU
__device__ __forceinline__ float fgelu(float v) {
  float u = 1.5957691216057308f * v * (1.0f + 0.044715f * v * v);
  return v / (1.0f + __expf(-u));
}

// ------ prep: one wave per row b: mean, bf16 casts, score-bias sbias --------
__global__ __launch_bounds__(256) void k_prep(const float* __restrict__ ti,
                                              const float* __restrict__ qwkb,
                                              const float* __restrict__ kbqb,
                                              u16* __restrict__ tib,
                                              u16* __restrict__ xsb,
                                              float* __restrict__ sbias) {
  int gw = (blockIdx.x * 256 + threadIdx.x) >> 6;   // row b
  int lane = threadIdx.x & 63;
  int d0 = lane * 8;
  float x[4][8];
#pragma unroll
  for (int t = 0; t < 4; t++) {
    const float* p = ti + ((size_t)t * BB + gw) * DIM + d0;
    *(float4*)&x[t][0] = *(const float4*)p;
    *(float4*)&x[t][4] = *(const float4*)(p + 4);
  }
  float m[8];
#pragma unroll
  for (int j = 0; j < 8; j++)
    m[j] = (x[0][j] + x[1][j] + x[2][j] + x[3][j]) * 0.25f;
#pragma unroll
  for (int t = 0; t < 4; t++) {
    ushort4 c0 = { f2b(x[t][0]), f2b(x[t][1]), f2b(x[t][2]), f2b(x[t][3]) };
    ushort4 c1 = { f2b(x[t][4]), f2b(x[t][5]), f2b(x[t][6]), f2b(x[t][7]) };
    u16* q = tib + ((size_t)t * BB + gw) * DIM + d0;
    *(ushort4*)q = c0; *(ushort4*)(q + 4) = c1;
  }
  {
    ushort4 c0 = { f2b(m[0]), f2b(m[1]), f2b(m[2]), f2b(m[3]) };
    ushort4 c1 = { f2b(m[4]), f2b(m[5]), f2b(m[6]), f2b(m[7]) };
    u16* q = xsb + (size_t)gw * DIM + d0;
    *(ushort4*)q = c0; *(ushort4*)(q + 4) = c1;
  }
#pragma unroll
  for (int t = 0; t < 4; t++) {
    const float* wp = qwkb + (size_t)t * DIM + d0;
    float4 w0 = *(const float4*)wp, w1 = *(const float4*)(wp + 4);
    float s = x[t][0]*w0.x + x[t][1]*w0.y + x[t][2]*w0.z + x[t][3]*w0.w
            + x[t][4]*w1.x + x[t][5]*w1.y + x[t][6]*w1.z + x[t][7]*w1.w;
    s = wsum(s);
    if (lane == 0) sbias[(size_t)t * BB + gw] = s + kbqb[t];
  }
}

// ------------- batched transpose+cast: (G,R,C) f32 -> (G,C,R) bf16 -----------
__global__ __launch_bounds__(256) void k_tcast(const float* __restrict__ in,
                                               u16* __restrict__ out,
                                               int R, int C) {
  __shared__ float tile[32][33];
  size_t gb = (size_t)blockIdx.z * R * C;
  in += gb; out += gb;
  int c0 = blockIdx.x * 32, r0 = blockIdx.y * 32;
  int tx = threadIdx.x & 31, ty = threadIdx.x >> 5;
#pragma unroll
  for (int j = 0; j < 4; j++)
    tile[ty + j * 8][tx] = in[(size_t)(r0 + ty + j * 8) * C + c0 + tx];
  __syncthreads();
#pragma unroll
  for (int j = 0; j < 4; j++)
    out[(size_t)(c0 + ty + j * 8) * R + r0 + tx] = f2b(tile[tx][ty + j * 8]);
}

// ---------------- plain cast f32 -> bf16 -------------------------------------
__global__ __launch_bounds__(256) void k_cast(const float* __restrict__ in,
                                              u16* __restrict__ out) {
  size_t i = ((size_t)blockIdx.x * 256 + threadIdx.x) * 4;
  float4 v = *(const float4*)(in + i);
  ushort4 b = { f2b(v.x), f2b(v.y), f2b(v.z), f2b(v.w) };
  *(ushort4*)(out + i) = b;
}

// --------------- small bias-vector precomputes -------------------------------
__global__ __launch_bounds__(256) void k_biasvec(const float* __restrict__ qw,
                                                 const float* __restrict__ kb,
                                                 const float* __restrict__ kw,
                                                 const float* __restrict__ qb,
                                                 float* __restrict__ qwkb,
                                                 float* __restrict__ kwqb,
                                                 float* __restrict__ kbqb) {
  int gw = (blockIdx.x * 256 + threadIdx.x) >> 6;
  int lane = threadIdx.x & 63;
  if (gw < 2048) {
    int t = gw >> 9, c = gw & 511;
    const float* row = qw + ((size_t)t * DIM + c) * DIM;
    const float* v = kb + (size_t)t * DIM;
    float s = 0;
#pragma unroll
    for (int j = 0; j < 8; j++) s += row[lane * 8 + j] * v[lane * 8 + j];
    s = wsum(s);
    if (lane == 0) qwkb[(size_t)t * DIM + c] = s;
  } else if (gw < 4096) {
    int t = (gw - 2048) >> 9, d = gw & 511;
    const float* row = kw + ((size_t)t * DIM + d) * DIM;
    const float* v = qb + (size_t)t * DIM;
    float s = 0;
#pragma unroll
    for (int j = 0; j < 8; j++) s += row[lane * 8 + j] * v[lane * 8 + j];
    s = wsum(s);
    if (lane == 0) kwqb[(size_t)t * DIM + d] = s;
  } else if (gw < 4100) {
    int t = gw - 4096;
    const float* a = kb + (size_t)t * DIM;
    const float* c = qb + (size_t)t * DIM;
    float s = 0;
#pragma unroll
    for (int j = 0; j < 8; j++) s += a[lane * 8 + j] * c[lane * 8 + j];
    s = wsum(s);
    if (lane == 0) kbqb[t] = s;
  }
}

// ------- 256x256 bf16 MFMA GEMM mainloop (NT), 512 thr, BK=64, swapped -------
// 128 FLOP/byte staged (2x the 128^2 tile) — staging-BW is the measured limit.
// Swizzle: LDS[row][p] = global chunk (p ^ (row&7)); reader XORs back.
__device__ __forceinline__ void gemm256(const u16* __restrict__ Ag, int lda,
                                        const u16* __restrict__ Bg, int ldb,
                                        int K, f32x4 acc[8][4]) {
  __shared__ __align__(16) u16 lA[16384];   // 256 x 64
  __shared__ __align__(16) u16 lB[16384];
  const int tid = threadIdx.x;              // 0..511
  const int lane = tid & 63;
  const int wave = tid >> 6;
  const int wm = wave >> 2, wn = wave & 3;  // 2 x 4 wave grid
  const int rl = lane & 15;
  const int q = lane >> 4;
  const int s = rl & 7;
  const u16* aP[4]; const u16* bP[4];
#pragma unroll
  for (int i = 0; i < 4; i++) {
    int c16 = tid + 512 * i;                // chunk index 0..2047
    int row = c16 >> 3;                     // 0..255
    int gch = (c16 & 7) ^ (row & 7);        // pre-swizzled global chunk
    aP[i] = Ag + (size_t)row * lda + gch * 8;
    bP[i] = Bg + (size_t)row * ldb + gch * 8;
  }
  const int abase = (wm * 128 + rl) * 64;
  const int bbase = (wn * 64 + rl) * 64;
  const int ch0 = (q ^ s) * 8;
  const int ch1 = ((4 + q) ^ s) * 8;
  const int nsteps = K >> 6;
  for (int k = 0; k < nsteps; ++k) {
    const int off = k * 64;
    __syncthreads();
#pragma unroll
    for (int i = 0; i < 4; i++) {
      GLOAD16(aP[i] + off, &lA[(tid + 512 * i) * 8]);
      GLOAD16(bP[i] + off, &lB[(tid + 512 * i) * 8]);
    }
    __syncthreads();
#pragma unroll
    for (int ks = 0; ks < 2; ks++) {
      const int co = ks ? ch1 : ch0;
      short8 bf[4];
#pragma unroll
      for (int nf = 0; nf < 4; nf++)
        bf[nf] = *(const short8*)&lB[bbase + nf * 1024 + co];
      __builtin_amdgcn_s_setprio(1);
#pragma unroll
      for (int mf = 0; mf < 8; mf++) {
        short8 af = *(const short8*)&lA[abase + mf * 1024 + co];
#pragma unroll
        for (int nf = 0; nf < 4; nf++)
          acc[mf][nf] = __builtin_amdgcn_mfma_f32_16x16x32_bf16(bf[nf], af,
                                                                acc[mf][nf], 0, 0, 0);
      }
      __builtin_amdgcn_s_setprio(0);
    }
  }
}

// ------- 128x128 bf16 MFMA GEMM mainloop (NT), BK=64, swapped (small GEMMs) --
__device__ __forceinline__ void gemm128(const u16* __restrict__ Ag, int lda,
                                        const u16* __restrict__ Bg, int ldb,
                                        int K, f32x4 acc[4][4]) {
  __shared__ __align__(16) u16 lA[8192];   // 128 x 64
  __shared__ __align__(16) u16 lB[8192];
  const int tid = threadIdx.x;
  const int lane = tid & 63;
  const int wave = tid >> 6;
  const int wm = wave >> 1, wn = wave & 1;
  const int rl = lane & 15;
  const int q = lane >> 4;
  const int s = rl & 7;
  const u16* aP[4]; const u16* bP[4];
#pragma unroll
  for (int i = 0; i < 4; i++) {
    int c16 = tid + 256 * i;
    int row = c16 >> 3;
    int gch = (c16 & 7) ^ (row & 7);
    aP[i] = Ag + (size_t)row * lda + gch * 8;
    bP[i] = Bg + (size_t)row * ldb + gch * 8;
  }
  const int arow = (wm * 64 + rl) * 64;
  const int brow = (wn * 64 + rl) * 64;
  const int ch0 = (q ^ s) * 8;
  const int ch1 = ((4 + q) ^ s) * 8;
  const int nsteps = K >> 6;
  for (int k = 0; k < nsteps; ++k) {
    const int off = k * 64;
    __syncthreads();
#pragma unroll
    for (int i = 0; i < 4; i++) {
      GLOAD16(aP[i] + off, &lA[(tid + 256 * i) * 8]);
      GLOAD16(bP[i] + off, &lB[(tid + 256 * i) * 8]);
    }
    __syncthreads();
#pragma unroll
    for (int ks = 0; ks < 2; ks++) {
      const int co = ks ? ch1 : ch0;
      short8 af[4], bf[4];
#pragma unroll
      for (int i = 0; i < 4; i++) {
        af[i] = *(const short8*)&lA[arow + i * 1024 + co];
        bf[i] = *(const short8*)&lB[brow + i * 1024 + co];
      }
      __builtin_amdgcn_s_setprio(1);
#pragma unroll
      for (int mi = 0; mi < 4; mi++)
#pragma unroll
        for (int ni = 0; ni < 4; ni++)
          acc[mi][ni] = __builtin_amdgcn_mfma_f32_16x16x32_bf16(bf[ni], af[mi],
                                                                acc[mi][ni], 0, 0, 0);
      __builtin_amdgcn_s_setprio(0);
    }
  }
}

// ---------------- expert up-GEMM: h = gelu(x@W1 + b1), bf16 out --------------
// 256x256 tile; lane owns (row=rl, 4 consecutive cols) -> ushort4 stores.
__global__ __launch_bounds__(512, 2) void k_gemm_up(const u16* __restrict__ xsb,
                                                 const u16* __restrict__ tib,
                                                 const u16* __restrict__ w1t,
                                                 const float* __restrict__ sb1,
                                                 const float* __restrict__ tb1,
                                                 u16* __restrict__ hbuf,
                                                 int row0, int SR) {
  int ge = blockIdx.z;
  const u16* A;
  const float* bias;
  if (ge < 4) { A = xsb; bias = sb1 + (size_t)ge * HDIM; }
  else {
    int te = ge - 4;
    A = tib + (size_t)(te >> 2) * BD;
    bias = tb1 + (size_t)te * HDIM;
  }
  A += (size_t)row0 * DIM;
  const u16* W = w1t + (size_t)ge * ((size_t)HDIM * DIM);
  int m0 = blockIdx.y * 256, n0 = blockIdx.x * 256;
  f32x4 acc[8][4] = {};
  gemm256(A + (size_t)m0 * DIM, DIM, W + (size_t)n0 * DIM, DIM, DIM, acc);
  u16* out = hbuf + (size_t)ge * ((size_t)SR * HDIM);
  const int lane = threadIdx.x & 63, wave = threadIdx.x >> 6;
  const int rl = lane & 15, c4 = (lane >> 4) * 4;
  const int wm = wave >> 2, wn = wave & 3;
#pragma unroll
  for (int mf = 0; mf < 8; mf++) {
    int row = m0 + wm * 128 + mf * 16 + rl;
#pragma unroll
    for (int nf = 0; nf < 4; nf++) {
      int col0 = n0 + wn * 64 + nf * 16 + c4;
      float4 bb = *(const float4*)(bias + col0);
      ushort4 y;
      y.x = f2b(fgelu(acc[mf][nf][0] + bb.x));
      y.y = f2b(fgelu(acc[mf][nf][1] + bb.y));
      y.z = f2b(fgelu(acc[mf][nf][2] + bb.z));
      y.w = f2b(fgelu(acc[mf][nf][3] + bb.w));
      *(ushort4*)(out + (size_t)row * HDIM + col0) = y;
    }
  }
}

// ---- down-GEMM: preLN bf16 = h@W2 + b2 + residual -> stk16[20][B][D] --------
__global__ __launch_bounds__(512, 2) void k_gemm_down(const u16* __restrict__ hbuf,
                                                   const u16* __restrict__ w2t,
                                                   const float* __restrict__ sb2,
                                                   const float* __restrict__ tb2,
                                                   const u16* __restrict__ xsb,
                                                   const u16* __restrict__ tib,
                                                   u16* __restrict__ stk16,
                                                   int row0, int SR) {
  int ge = blockIdx.z;
  int m0 = blockIdx.y * 256, n0 = blockIdx.x * 256;
  const u16* Ag = hbuf + (size_t)ge * ((size_t)SR * HDIM) + (size_t)m0 * HDIM;
  const u16* Bg = w2t + (size_t)ge * ((size_t)DIM * HDIM) + (size_t)n0 * HDIM;
  f32x4 acc[8][4] = {};
  gemm256(Ag, HDIM, Bg, HDIM, HDIM, acc);
  const float* bias; const u16* resb;
  int te = ge - 4;
  if (ge < 4) { bias = sb2 + (size_t)ge * DIM; resb = xsb; }
  else { bias = tb2 + (size_t)te * DIM; resb = tib + (size_t)(te >> 2) * BD; }
  const int lane = threadIdx.x & 63, wave = threadIdx.x >> 6;
  const int rl = lane & 15, c4 = (lane >> 4) * 4;
  const int wm = wave >> 2, wn = wave & 3;
  u16* outb = stk16 + (size_t)ge * BD;
#pragma unroll
  for (int mf = 0; mf < 8; mf++) {
    int grow = row0 + m0 + wm * 128 + mf * 16 + rl;
#pragma unroll
    for (int nf = 0; nf < 4; nf++) {
      int col0 = n0 + wn * 64 + nf * 16 + c4;
      float4 bb = *(const float4*)(bias + col0);
      ushort4 rr = *(const ushort4*)(resb + (size_t)grow * DIM + col0);
      ushort4 y;
      y.x = f2b(acc[mf][nf][0] + bb.x + b2f(rr.x));
      y.y = f2b(acc[mf][nf][1] + bb.y + b2f(rr.y));
      y.z = f2b(acc[mf][nf][2] + bb.z + b2f(rr.z));
      y.w = f2b(acc[mf][nf][3] + bb.w + b2f(rr.w));
      *(ushort4*)(outb + (size_t)grow * DIM + col0) = y;
    }
  }
}

// ---------------- MT[t] = kw[t] @ qw[t]^T  (bf16 out) ------------------------
__global__ __launch_bounds__(256) void k_gemm_mt(const u16* __restrict__ kwb,
                                                 const u16* __restrict__ qwb,
                                                 u16* __restrict__ mt) {
  int t = blockIdx.z;
  int m0 = blockIdx.y * 128, n0 = blockIdx.x * 128;
  f32x4 acc[4][4] = {};
  gemm128(kwb + (size_t)t * D2 + (size_t)m0 * DIM, DIM,
          qwb + (size_t)t * D2 + (size_t)n0 * DIM, DIM, DIM, acc);
  const int lane = threadIdx.x & 63, wave = threadIdx.x >> 6;
  const int rl = lane & 15, c4 = (lane >> 4) * 4;
  const int wm = wave >> 1, wn = wave & 1;
#pragma unroll
  for (int mf = 0; mf < 4; mf++) {
    int row = m0 + wm * 64 + mf * 16 + rl;
#pragma unroll
    for (int nf = 0; nf < 4; nf++) {
      int col0 = n0 + wn * 64 + nf * 16 + c4;
      ushort4 y = { f2b(acc[mf][nf][0]), f2b(acc[mf][nf][1]),
                    f2b(acc[mf][nf][2]), f2b(acc[mf][nf][3]) };
      *(ushort4*)(mt + (size_t)t * D2 + (size_t)row * DIM + col0) = y;
    }
  }
}

// ------------- qkb[t] = bf16(x[t] @ MT[t]^T + kwqb[t]) -----------------------
__global__ __launch_bounds__(256) void k_gemm_qk(const u16* __restrict__ tib,
                                                 const u16* __restrict__ mt,
                                                 const float* __restrict__ kwqb,
                                                 u16* __restrict__ qkb) {
  int t = blockIdx.z;
  int m0 = blockIdx.y * 128, n0 = blockIdx.x * 128;
  f32x4 acc[4][4] = {};
  gemm128(tib + (size_t)t * BD + (size_t)m0 * DIM, DIM,
          mt + (size_t)t * D2 + (size_t)n0 * DIM, DIM, DIM, acc);
  const int lane = threadIdx.x & 63, wave = threadIdx.x >> 6;
  const int rl = lane & 15, c4 = (lane >> 4) * 4;
  const int wm = wave >> 1, wn = wave & 1;
#pragma unroll
  for (int mf = 0; mf < 4; mf++) {
    int row = m0 + wm * 64 + mf * 16 + rl;
#pragma unroll
    for (int nf = 0; nf < 4; nf++) {
      int col0 = n0 + wn * 64 + nf * 16 + c4;
      float4 bb = *(const float4*)(kwqb + (size_t)t * DIM + col0);
      ushort4 y;
      y.x = f2b(acc[mf][nf][0] + bb.x);
      y.y = f2b(acc[mf][nf][1] + bb.y);
      y.z = f2b(acc[mf][nf][2] + bb.z);
      y.w = f2b(acc[mf][nf][3] + bb.w);
      *(ushort4*)(qkb + (size_t)t * BD + (size_t)row * DIM + col0) = y;
    }
  }
}

// ---- fused LN + scores + softmax + gating (one wave per (t,b)) --------------
__global__ __launch_bounds__(256) void k_score(const u16* __restrict__ stk16,
                                               const u16* __restrict__ qkb,
                                               const float* __restrict__ sbias,
                                               const float* __restrict__ sg,
                                               const float* __restrict__ sbt,
                                               const float* __restrict__ tg,
                                               const float* __restrict__ tbt,
                                               float* __restrict__ stacked,
                                               float* __restrict__ gated,
                                               float* __restrict__ wout) {
  int gw = (blockIdx.x * 256 + threadIdx.x) >> 6;
  int lane = threadIdx.x & 63;
  int b = gw & (BB - 1), t = gw >> 12;
  int d0 = lane * 8;
  size_t rowoff = ((size_t)t * BB + b) * DIM + d0;
  float qr[8];
  {
    ushort4 q0 = *(const ushort4*)(qkb + rowoff);
    ushort4 q1 = *(const ushort4*)(qkb + rowoff + 4);
    qr[0] = b2f(q0.x); qr[1] = b2f(q0.y); qr[2] = b2f(q0.z); qr[3] = b2f(q0.w);
    qr[4] = b2f(q1.x); qr[5] = b2f(q1.y); qr[6] = b2f(q1.z); qr[7] = b2f(q1.w);
  }
  float stv[8][8];
  float dots[8];
#pragma unroll
  for (int n = 0; n < 8; n++) {
    int e = (n < 4) ? n : (4 + t * 4 + (n - 4));
    const u16* sp = stk16 + ((size_t)e * BB + b) * DIM + d0;
    ushort4 v0 = *(const ushort4*)sp;
    ushort4 v1 = *(const ushort4*)(sp + 4);
    float v[8] = { b2f(v0.x), b2f(v0.y), b2f(v0.z), b2f(v0.w),
                   b2f(v1.x), b2f(v1.y), b2f(v1.z), b2f(v1.w) };
    float S = 0, Q = 0;
#pragma unroll
    for (int j = 0; j < 8; j++) { S += v[j]; Q += v[j] * v[j]; }
    S = wsum(S); Q = wsum(Q);
    float mu = S * (1.0f / DIM);
    float var = Q * (1.0f / DIM) - mu * mu;
    float rs = rsqrtf(var + 1e-5f);
    const float* gp; const float* bp;
    if (n < 4) { gp = sg + (size_t)n * DIM; bp = sbt + (size_t)n * DIM; }
    else {
      int te = t * 4 + (n - 4);
      gp = tg + (size_t)te * DIM; bp = tbt + (size_t)te * DIM;
    }
    float4 g0 = *(const float4*)(gp + d0), g1 = *(const float4*)(gp + d0 + 4);
    float4 b0 = *(const float4*)(bp + d0), b1 = *(const float4*)(bp + d0 + 4);
    float gv[8] = { g0.x, g0.y, g0.z, g0.w, g1.x, g1.y, g1.z, g1.w };
    float bv[8] = { b0.x, b0.y, b0.z, b0.w, b1.x, b1.y, b1.z, b1.w };
    float dd = 0;
#pragma unroll
    for (int j = 0; j < 8; j++) {
      float y = (v[j] - mu) * rs * gv[j] + bv[j];
      stv[n][j] = y;
      dd += y * qr[j];
    }
    float* so = stacked + (((size_t)t * 8 + n) * BB + b) * DIM + d0;
    *(float4*)so = *(float4*)&stv[n][0];
    *(float4*)(so + 4) = *(float4*)&stv[n][4];
    dots[n] = wsum(dd);
  }
  float sb = sbias[(size_t)t * BB + b];
  const float inv = 0.04419417382415922f;  // 1/sqrt(512)
  float sc[8], e[8];
  float mx = -1e30f;
#pragma unroll
  for (int n = 0; n < 8; n++) { sc[n] = (dots[n] + sb) * inv; mx = fmaxf(mx, sc[n]); }
  float den = 0;
#pragma unroll
  for (int n = 0; n < 8; n++) { e[n] = expf(sc[n] - mx); den += e[n]; }
  float rden = 1.0f / den;
  float wv[8];
#pragma unroll
  for (int n = 0; n < 8; n++) wv[n] = e[n] * rden;
  float wsel = 0;
#pragma unroll
  for (int n = 0; n < 8; n++) wsel = (lane == n) ? wv[n] : wsel;
  if (lane < 8) wout[((size_t)t * BB + b) * 8 + lane] = wsel;
  float g[8];
#pragma unroll
  for (int j = 0; j < 8; j++) {
    float s = 0;
#pragma unroll
    for (int n = 0; n < 8; n++) s += wv[n] * stv[n][j];
    g[j] = s;
  }
  float* go = gated + rowoff;
  *(float4*)(go) = *(float4*)&g[0];
  *(float4*)(go + 4) = *(float4*)&g[4];
}

// ============================ host launcher ==================================
extern "C" void kernel_launch(void* const* d_in, const int* in_sizes, int n_in,
                              void* d_out, int out_size, void* d_ws, size_t ws_size,
                              hipStream_t stream) {
  const float* ti  = (const float*)d_in[0];
  const float* sw1 = (const float*)d_in[1];
  const float* sb1 = (const float*)d_in[2];
  const float* sw2 = (const float*)d_in[3];
  const float* sb2 = (const float*)d_in[4];
  const float* sg  = (const float*)d_in[5];
  const float* sbt = (const float*)d_in[6];
  const float* tw1 = (const float*)d_in[7];
  const float* tb1 = (const float*)d_in[8];
  const float* tw2 = (const float*)d_in[9];
  const float* tb2 = (const float*)d_in[10];
  const float* tg  = (const float*)d_in[11];
  const float* tbt = (const float*)d_in[12];
  const float* qw  = (const float*)d_in[13];
  const float* qb  = (const float*)d_in[14];
  const float* kw  = (const float*)d_in[15];
  const float* kb  = (const float*)d_in[16];

  float* out = (float*)d_out;
  float* gated   = out;                                   // T*B*D
  float* weights = out + (size_t)TT * BB * DIM;           // T*B*8
  float* stacked = weights + (size_t)TT * BB * 8;         // T*8*B*D

  char* ws = (char*)d_ws;
  u16*   tib   = (u16*)(ws);                    // 16,777,216
  u16*   xsb   = (u16*)(ws + 16777216);         //  4,194,304
  u16*   w1t   = (u16*)(ws + 20971520);         // 20,971,520
  u16*   w2t   = (u16*)(ws + 41943040);         // 20,971,520
  u16*   qwb   = (u16*)(ws + 62914560);         //  2,097,152
  u16*   kwb   = (u16*)(ws + 65011712);         //  2,097,152
  u16*   mt    = (u16*)(ws + 67108864);         //  2,097,152
  float* sbias = (float*)(ws + 69206016);       //     65,536
  float* qwkb  = (float*)(ws + 69271552);       //      8,192
  float* kwqb  = (float*)(ws + 69279744);       //      8,192
  float* kbqb  = (float*)(ws + 69287936);       //      1,024
  u16*   qkb   = (u16*)(ws + 69288960);         // 16,777,216
  u16*   stk16 = (u16*)(ws + 86066176);         // 83,886,080 (20*B*D bf16)
  u16*   hbuf  = (u16*)(ws + 169952256);        // SR*HDIM*2*20

  const size_t hoff = 169952256;
  int SR = 512;
  if (ws_size >= hoff + (size_t)NEXP * BB * HDIM * 2) SR = BB;           // 338 MB
  else if (ws_size >= hoff + (size_t)NEXP * 1024 * HDIM * 2) SR = 1024;

  // weight / gate preprocessing
  k_tcast<<<dim3(32, 16, 4), 256, 0, stream>>>(sw1, w1t, DIM, HDIM);
  k_tcast<<<dim3(32, 16, 16), 256, 0, stream>>>(tw1, w1t + (size_t)4 * HDIM * DIM, DIM, HDIM);
  k_tcast<<<dim3(16, 32, 4), 256, 0, stream>>>(sw2, w2t, HDIM, DIM);
  k_tcast<<<dim3(16, 32, 16), 256, 0, stream>>>(tw2, w2t + (size_t)4 * DIM * HDIM, HDIM, DIM);
  k_cast<<<1024, 256, 0, stream>>>(qw, qwb);
  k_cast<<<1024, 256, 0, stream>>>(kw, kwb);
  k_biasvec<<<1025, 256, 0, stream>>>(qw, kb, kw, qb, qwkb, kwqb, kbqb);
  k_prep<<<1024, 256, 0, stream>>>(ti, qwkb, kbqb, tib, xsb, sbias);
  k_gemm_mt<<<dim3(4, 4, 4), 256, 0, stream>>>(kwb, qwb, mt);

  // expert FFNs: 256x256 tiles (2x arithmetic intensity), BK=64 single-buffer
  for (int row0 = 0; row0 < BB; row0 += SR) {
    k_gemm_up<<<dim3(4, SR / 256, NEXP), 512, 0, stream>>>(xsb, tib, w1t, sb1, tb1,
                                                           hbuf, row0, SR);
    k_gemm_down<<<dim3(2, SR / 256, NEXP), 512, 0, stream>>>(hbuf, w2t, sb2, tb2,
                                                             xsb, tib, stk16, row0, SR);
  }

  k_gemm_qk<<<dim3(4, 32, 4), 256, 0, stream>>>(tib, mt, kwqb, qkb);
  k_score<<<4096, 256, 0, stream>>>(stk16, qkb, sbias, sg, sbt, tg, tbt,
                                    stacked, gated, weights);
}

// Round 14
// 516.368 us; speedup vs baseline: 1.0439x; 1.0406x over previous
//
#include <hip/hip_runtime.h>
#include <math.h>

typedef unsigned short u16;
typedef short short8 __attribute__((ext_vector_type(8)));
typedef float f32x4 __attribute__((ext_vector_type(4)));

#define TT 4
#define BB 4096
#define DIM 512
#define HDIM 1024
#define BD (BB*DIM)      // 2097152
#define D2 (DIM*DIM)     // 262144
#define NEXP 20

#define GLOAD16(gp, lp) __builtin_amdgcn_global_load_lds( \
    (__attribute__((address_space(1))) void*)(void*)(gp), \
    (__attribute__((address_space(3))) void*)(void*)(lp), 16, 0, 0)

__device__ __forceinline__ u16 f2b(float f) {
  union { float f; unsigned u; } x; x.f = f;
  unsigned r = x.u + 0x7FFFu + ((x.u >> 16) & 1u);
  return (u16)(r >> 16);
}
__device__ __forceinline__ float b2f(u16 v) {
  union { unsigned u; float f; } x; x.u = ((unsigned)v) << 16; return x.f;
}

__device__ __forceinline__ float wsum(float v) {
#pragma unroll
  for (int o = 32; o > 0; o >>= 1) v += __shfl_xor(v, o);
  return v;
}

// fast exact-enough GELU
__device__ __forceinline__ float fgelu(float v) {
  float u = 1.5957691216057308f * v * (1.0f + 0.044715f * v * v);
  return v / (1.0f + __expf(-u));
}

// ------ prep: one wave per row b: mean, bf16 casts, score-bias sbias --------
__global__ __launch_bounds__(256) void k_prep(const float* __restrict__ ti,
                                              const float* __restrict__ qwkb,
                                              const float* __restrict__ kbqb,
                                              u16* __restrict__ tib,
                                              u16* __restrict__ xsb,
                                              float* __restrict__ sbias) {
  int gw = (blockIdx.x * 256 + threadIdx.x) >> 6;   // row b
  int lane = threadIdx.x & 63;
  int d0 = lane * 8;
  float x[4][8];
#pragma unroll
  for (int t = 0; t < 4; t++) {
    const float* p = ti + ((size_t)t * BB + gw) * DIM + d0;
    *(float4*)&x[t][0] = *(const float4*)p;
    *(float4*)&x[t][4] = *(const float4*)(p + 4);
  }
  float m[8];
#pragma unroll
  for (int j = 0; j < 8; j++)
    m[j] = (x[0][j] + x[1][j] + x[2][j] + x[3][j]) * 0.25f;
#pragma unroll
  for (int t = 0; t < 4; t++) {
    ushort4 c0 = { f2b(x[t][0]), f2b(x[t][1]), f2b(x[t][2]), f2b(x[t][3]) };
    ushort4 c1 = { f2b(x[t][4]), f2b(x[t][5]), f2b(x[t][6]), f2b(x[t][7]) };
    u16* q = tib + ((size_t)t * BB + gw) * DIM + d0;
    *(ushort4*)q = c0; *(ushort4*)(q + 4) = c1;
  }
  {
    ushort4 c0 = { f2b(m[0]), f2b(m[1]), f2b(m[2]), f2b(m[3]) };
    ushort4 c1 = { f2b(m[4]), f2b(m[5]), f2b(m[6]), f2b(m[7]) };
    u16* q = xsb + (size_t)gw * DIM + d0;
    *(ushort4*)q = c0; *(ushort4*)(q + 4) = c1;
  }
#pragma unroll
  for (int t = 0; t < 4; t++) {
    const float* wp = qwkb + (size_t)t * DIM + d0;
    float4 w0 = *(const float4*)wp, w1 = *(const float4*)(wp + 4);
    float s = x[t][0]*w0.x + x[t][1]*w0.y + x[t][2]*w0.z + x[t][3]*w0.w
            + x[t][4]*w1.x + x[t][5]*w1.y + x[t][6]*w1.z + x[t][7]*w1.w;
    s = wsum(s);
    if (lane == 0) sbias[(size_t)t * BB + gw] = s + kbqb[t];
  }
}

// ------------- batched transpose+cast: (G,R,C) f32 -> (G,C,R) bf16 -----------
__global__ __launch_bounds__(256) void k_tcast(const float* __restrict__ in,
                                               u16* __restrict__ out,
                                               int R, int C) {
  __shared__ float tile[32][33];
  size_t gb = (size_t)blockIdx.z * R * C;
  in += gb; out += gb;
  int c0 = blockIdx.x * 32, r0 = blockIdx.y * 32;
  int tx = threadIdx.x & 31, ty = threadIdx.x >> 5;
#pragma unroll
  for (int j = 0; j < 4; j++)
    tile[ty + j * 8][tx] = in[(size_t)(r0 + ty + j * 8) * C + c0 + tx];
  __syncthreads();
#pragma unroll
  for (int j = 0; j < 4; j++)
    out[(size_t)(c0 + ty + j * 8) * R + r0 + tx] = f2b(tile[tx][ty + j * 8]);
}

// ---------------- plain cast f32 -> bf16 -------------------------------------
__global__ __launch_bounds__(256) void k_cast(const float* __restrict__ in,
                                              u16* __restrict__ out) {
  size_t i = ((size_t)blockIdx.x * 256 + threadIdx.x) * 4;
  float4 v = *(const float4*)(in + i);
  ushort4 b = { f2b(v.x), f2b(v.y), f2b(v.z), f2b(v.w) };
  *(ushort4*)(out + i) = b;
}

// --------------- small bias-vector precomputes -------------------------------
__global__ __launch_bounds__(256) void k_biasvec(const float* __restrict__ qw,
                                                 const float* __restrict__ kb,
                                                 const float* __restrict__ kw,
                                                 const float* __restrict__ qb,
                                                 float* __restrict__ qwkb,
                                                 float* __restrict__ kwqb,
                                                 float* __restrict__ kbqb) {
  int gw = (blockIdx.x * 256 + threadIdx.x) >> 6;
  int lane = threadIdx.x & 63;
  if (gw < 2048) {
    int t = gw >> 9, c = gw & 511;
    const float* row = qw + ((size_t)t * DIM + c) * DIM;
    const float* v = kb + (size_t)t * DIM;
    float s = 0;
#pragma unroll
    for (int j = 0; j < 8; j++) s += row[lane * 8 + j] * v[lane * 8 + j];
    s = wsum(s);
    if (lane == 0) qwkb[(size_t)t * DIM + c] = s;
  } else if (gw < 4096) {
    int t = (gw - 2048) >> 9, d = gw & 511;
    const float* row = kw + ((size_t)t * DIM + d) * DIM;
    const float* v = qb + (size_t)t * DIM;
    float s = 0;
#pragma unroll
    for (int j = 0; j < 8; j++) s += row[lane * 8 + j] * v[lane * 8 + j];
    s = wsum(s);
    if (lane == 0) kwqb[(size_t)t * DIM + d] = s;
  } else if (gw < 4100) {
    int t = gw - 4096;
    const float* a = kb + (size_t)t * DIM;
    const float* c = qb + (size_t)t * DIM;
    float s = 0;
#pragma unroll
    for (int j = 0; j < 8; j++) s += a[lane * 8 + j] * c[lane * 8 + j];
    s = wsum(s);
    if (lane == 0) kbqb[t] = s;
  }
}

// ---- 128x128 bf16 MFMA GEMM, BK=32, TRIPLE-RING counted-vmcnt pipeline ------
// Both A and B ring depth-2: end-of-iter vmcnt(4) keeps tile k+2's 4 loads
// in flight across the barrier. 48 KB LDS -> 3 blocks/CU.
// Overwrite safety: buf[(k+2)%3] last read at iter k-1, behind that barrier.
template <bool SWAPPED>
__device__ __forceinline__ void gemm128r(const u16* __restrict__ Ag, int lda,
                                         const u16* __restrict__ Bg, int ldb,
                                         int K, f32x4 acc[4][4]) {
  __shared__ __align__(16) u16 lA[3][4096];   // 3 x (128 x 32)
  __shared__ __align__(16) u16 lB[3][4096];
  const int tid = threadIdx.x;
  const int lane = tid & 63;
  const int wave = tid >> 6;
  const int wm = wave >> 1, wn = wave & 1;
  const int rl = lane & 15;
  const int gc = ((tid & 3) ^ ((tid >> 3) & 3)) * 8;    // pre-swizzled src chunk
  const int hs = ((lane >> 4) ^ ((rl >> 1) & 3)) * 8;   // swizzled read chunk
  const u16* a0 = Ag + (size_t)(tid >> 2) * lda + gc;
  const u16* a1 = a0 + (size_t)64 * lda;
  const u16* b0 = Bg + (size_t)(tid >> 2) * ldb + gc;
  const u16* b1 = b0 + (size_t)64 * ldb;
  const int ao = (wm * 64 + rl) * 32 + hs;
  const int bo = (wn * 64 + rl) * 32 + hs;
  const int nst = K >> 5;
  // prologue: stage tiles 0 (oldest) and 1
  GLOAD16(a0, &lA[0][tid * 8]);
  GLOAD16(a1, &lA[0][2048 + tid * 8]);
  GLOAD16(b0, &lB[0][tid * 8]);
  GLOAD16(b1, &lB[0][2048 + tid * 8]);
  GLOAD16(a0 + 32, &lA[1][tid * 8]);
  GLOAD16(a1 + 32, &lA[1][2048 + tid * 8]);
  GLOAD16(b0 + 32, &lB[1][tid * 8]);
  GLOAD16(b1 + 32, &lB[1][2048 + tid * 8]);
  asm volatile("s_waitcnt vmcnt(4)" ::: "memory");  // tile0 landed, tile1 in flight
  __builtin_amdgcn_s_barrier();
  __builtin_amdgcn_sched_barrier(0);
  for (int k = 0; k < nst; ++k) {
    const int cur = k % 3;
    if (k + 2 < nst) {                   // issue tile k+2 into ring slot
      const int off = (k + 2) * 32;
      const int nb = (k + 2) % 3;
      GLOAD16(a0 + off, &lA[nb][tid * 8]);
      GLOAD16(a1 + off, &lA[nb][2048 + tid * 8]);
      GLOAD16(b0 + off, &lB[nb][tid * 8]);
      GLOAD16(b1 + off, &lB[nb][2048 + tid * 8]);
    }
    short8 af[4], bf[4];
#pragma unroll
    for (int i = 0; i < 4; i++) {
      af[i] = *(const short8*)&lA[cur][ao + i * 512];
      bf[i] = *(const short8*)&lB[cur][bo + i * 512];
    }
    __builtin_amdgcn_s_setprio(1);
    if (SWAPPED) {
#pragma unroll
      for (int mi = 0; mi < 4; mi++)
#pragma unroll
        for (int ni = 0; ni < 4; ni++)
          acc[mi][ni] = __builtin_amdgcn_mfma_f32_16x16x32_bf16(bf[ni], af[mi],
                                                                acc[mi][ni], 0, 0, 0);
    } else {
#pragma unroll
      for (int mi = 0; mi < 4; mi++)
#pragma unroll
        for (int ni = 0; ni < 4; ni++)
          acc[mi][ni] = __builtin_amdgcn_mfma_f32_16x16x32_bf16(af[mi], bf[ni],
                                                                acc[mi][ni], 0, 0, 0);
    }
    __builtin_amdgcn_s_setprio(0);
    // counted wait: tile k+1 must land; tile k+2 stays in flight (never drain)
    if (k + 2 < nst) asm volatile("s_waitcnt vmcnt(4)" ::: "memory");
    else             asm volatile("s_waitcnt vmcnt(0)" ::: "memory");
    __builtin_amdgcn_s_barrier();
    __builtin_amdgcn_sched_barrier(0);
  }
}

// ---------------- expert up-GEMM: h = gelu(x@W1 + b1), bf16 out --------------
// non-swapped layout (r11-proven): row=(lane>>4)*4+r, col=lane&15.
__global__ __launch_bounds__(256) void k_gemm_up(const u16* __restrict__ xsb,
                                                 const u16* __restrict__ tib,
                                                 const u16* __restrict__ w1t,
                                                 const float* __restrict__ sb1,
                                                 const float* __restrict__ tb1,
                                                 u16* __restrict__ hbuf,
                                                 int row0, int SR) {
  int ge = blockIdx.z;
  const u16* A;
  const float* bias;
  if (ge < 4) { A = xsb; bias = sb1 + (size_t)ge * HDIM; }
  else {
    int te = ge - 4;
    A = tib + (size_t)(te >> 2) * BD;
    bias = tb1 + (size_t)te * HDIM;
  }
  A += (size_t)row0 * DIM;
  const u16* W = w1t + (size_t)ge * ((size_t)HDIM * DIM);
  int m0 = blockIdx.y * 128, n0 = blockIdx.x * 128;
  f32x4 acc[4][4] = {};
  gemm128r<false>(A + (size_t)m0 * DIM, DIM, W + (size_t)n0 * DIM, DIM, DIM, acc);
  u16* out = hbuf + (size_t)ge * ((size_t)SR * HDIM);
  const int lane = threadIdx.x & 63, wave = threadIdx.x >> 6;
  const int rbase = m0 + (wave >> 1) * 64 + (lane >> 4) * 4;
  const int cbase = n0 + (wave & 1) * 64 + (lane & 15);
#pragma unroll
  for (int mi = 0; mi < 4; mi++)
#pragma unroll
    for (int ni = 0; ni < 4; ni++)
#pragma unroll
      for (int r = 0; r < 4; r++) {
        int row = rbase + mi * 16 + r;
        int col = cbase + ni * 16;
        float v = acc[mi][ni][r] + bias[col];
        out[(size_t)row * HDIM + col] = f2b(fgelu(v));
      }
}

// ---- down-GEMM: preLN bf16 = h@W2 + b2 + residual -> stk16[20][B][D] --------
// swapped layout: lane owns (row=rl, 4 consecutive cols) -> ushort4 stores.
__global__ __launch_bounds__(256) void k_gemm_down(const u16* __restrict__ hbuf,
                                                   const u16* __restrict__ w2t,
                                                   const float* __restrict__ sb2,
                                                   const float* __restrict__ tb2,
                                                   const u16* __restrict__ xsb,
                                                   const u16* __restrict__ tib,
                                                   u16* __restrict__ stk16,
                                                   int row0, int SR) {
  int ge = blockIdx.z;
  int m0 = blockIdx.y * 128, n0 = blockIdx.x * 128;
  const u16* Ag = hbuf + (size_t)ge * ((size_t)SR * HDIM) + (size_t)m0 * HDIM;
  const u16* Bg = w2t + (size_t)ge * ((size_t)DIM * HDIM) + (size_t)n0 * HDIM;
  f32x4 acc[4][4] = {};
  gemm128r<true>(Ag, HDIM, Bg, HDIM, HDIM, acc);
  const float* bias; const u16* resb;
  int te = ge - 4;
  if (ge < 4) { bias = sb2 + (size_t)ge * DIM; resb = xsb; }
  else { bias = tb2 + (size_t)te * DIM; resb = tib + (size_t)(te >> 2) * BD; }
  const int lane = threadIdx.x & 63, wave = threadIdx.x >> 6;
  const int rl = lane & 15, c4 = (lane >> 4) * 4;
  const int wm = wave >> 1, wn = wave & 1;
  u16* outb = stk16 + (size_t)ge * BD;
#pragma unroll
  for (int mf = 0; mf < 4; mf++) {
    int grow = row0 + m0 + wm * 64 + mf * 16 + rl;
#pragma unroll
    for (int nf = 0; nf < 4; nf++) {
      int col0 = n0 + wn * 64 + nf * 16 + c4;
      float4 bb = *(const float4*)(bias + col0);
      ushort4 rr = *(const ushort4*)(resb + (size_t)grow * DIM + col0);
      ushort4 y;
      y.x = f2b(acc[mf][nf][0] + bb.x + b2f(rr.x));
      y.y = f2b(acc[mf][nf][1] + bb.y + b2f(rr.y));
      y.z = f2b(acc[mf][nf][2] + bb.z + b2f(rr.z));
      y.w = f2b(acc[mf][nf][3] + bb.w + b2f(rr.w));
      *(ushort4*)(outb + (size_t)grow * DIM + col0) = y;
    }
  }
}

// ---------------- MT[t] = kw[t] @ qw[t]^T  (bf16 out) ------------------------
__global__ __launch_bounds__(256) void k_gemm_mt(const u16* __restrict__ kwb,
                                                 const u16* __restrict__ qwb,
                                                 u16* __restrict__ mt) {
  int t = blockIdx.z;
  int m0 = blockIdx.y * 128, n0 = blockIdx.x * 128;
  f32x4 acc[4][4] = {};
  gemm128r<true>(kwb + (size_t)t * D2 + (size_t)m0 * DIM, DIM,
                 qwb + (size_t)t * D2 + (size_t)n0 * DIM, DIM, DIM, acc);
  const int lane = threadIdx.x & 63, wave = threadIdx.x >> 6;
  const int rl = lane & 15, c4 = (lane >> 4) * 4;
  const int wm = wave >> 1, wn = wave & 1;
#pragma unroll
  for (int mf = 0; mf < 4; mf++) {
    int row = m0 + wm * 64 + mf * 16 + rl;
#pragma unroll
    for (int nf = 0; nf < 4; nf++) {
      int col0 = n0 + wn * 64 + nf * 16 + c4;
      ushort4 y = { f2b(acc[mf][nf][0]), f2b(acc[mf][nf][1]),
                    f2b(acc[mf][nf][2]), f2b(acc[mf][nf][3]) };
      *(ushort4*)(mt + (size_t)t * D2 + (size_t)row * DIM + col0) = y;
    }
  }
}

// ------------- qkb[t] = bf16(x[t] @ MT[t]^T + kwqb[t]) -----------------------
__global__ __launch_bounds__(256) void k_gemm_qk(const u16* __restrict__ tib,
                                                 const u16* __restrict__ mt,
                                                 const float* __restrict__ kwqb,
                                                 u16* __restrict__ qkb) {
  int t = blockIdx.z;
  int m0 = blockIdx.y * 128, n0 = blockIdx.x * 128;
  f32x4 acc[4][4] = {};
  gemm128r<true>(tib + (size_t)t * BD + (size_t)m0 * DIM, DIM,
                 mt + (size_t)t * D2 + (size_t)n0 * DIM, DIM, DIM, acc);
  const int lane = threadIdx.x & 63, wave = threadIdx.x >> 6;
  const int rl = lane & 15, c4 = (lane >> 4) * 4;
  const int wm = wave >> 1, wn = wave & 1;
#pragma unroll
  for (int mf = 0; mf < 4; mf++) {
    int row = m0 + wm * 64 + mf * 16 + rl;
#pragma unroll
    for (int nf = 0; nf < 4; nf++) {
      int col0 = n0 + wn * 64 + nf * 16 + c4;
      float4 bb = *(const float4*)(kwqb + (size_t)t * DIM + col0);
      ushort4 y;
      y.x = f2b(acc[mf][nf][0] + bb.x);
      y.y = f2b(acc[mf][nf][1] + bb.y);
      y.z = f2b(acc[mf][nf][2] + bb.z);
      y.w = f2b(acc[mf][nf][3] + bb.w);
      *(ushort4*)(qkb + (size_t)t * BD + (size_t)row * DIM + col0) = y;
    }
  }
}

// ---- fused LN + scores + softmax + gating (one wave per (t,b)) --------------
__global__ __launch_bounds__(256) void k_score(const u16* __restrict__ stk16,
                                               const u16* __restrict__ qkb,
                                               const float* __restrict__ sbias,
                                               const float* __restrict__ sg,
                                               const float* __restrict__ sbt,
                                               const float* __restrict__ tg,
                                               const float* __restrict__ tbt,
                                               float* __restrict__ stacked,
                                               float* __restrict__ gated,
                                               float* __restrict__ wout) {
  int gw = (blockIdx.x * 256 + threadIdx.x) >> 6;
  int lane = threadIdx.x & 63;
  int b = gw & (BB - 1), t = gw >> 12;
  int d0 = lane * 8;
  size_t rowoff = ((size_t)t * BB + b) * DIM + d0;
  float qr[8];
  {
    ushort4 q0 = *(const ushort4*)(qkb + rowoff);
    ushort4 q1 = *(const ushort4*)(qkb + rowoff + 4);
    qr[0] = b2f(q0.x); qr[1] = b2f(q0.y); qr[2] = b2f(q0.z); qr[3] = b2f(q0.w);
    qr[4] = b2f(q1.x); qr[5] = b2f(q1.y); qr[6] = b2f(q1.z); qr[7] = b2f(q1.w);
  }
  float stv[8][8];
  float dots[8];
#pragma unroll
  for (int n = 0; n < 8; n++) {
    int e = (n < 4) ? n : (4 + t * 4 + (n - 4));
    const u16* sp = stk16 + ((size_t)e * BB + b) * DIM + d0;
    ushort4 v0 = *(const ushort4*)sp;
    ushort4 v1 = *(const ushort4*)(sp + 4);
    float v[8] = { b2f(v0.x), b2f(v0.y), b2f(v0.z), b2f(v0.w),
                   b2f(v1.x), b2f(v1.y), b2f(v1.z), b2f(v1.w) };
    float S = 0, Q = 0;
#pragma unroll
    for (int j = 0; j < 8; j++) { S += v[j]; Q += v[j] * v[j]; }
    S = wsum(S); Q = wsum(Q);
    float mu = S * (1.0f / DIM);
    float var = Q * (1.0f / DIM) - mu * mu;
    float rs = rsqrtf(var + 1e-5f);
    const float* gp; const float* bp;
    if (n < 4) { gp = sg + (size_t)n * DIM; bp = sbt + (size_t)n * DIM; }
    else {
      int te = t * 4 + (n - 4);
      gp = tg + (size_t)te * DIM; bp = tbt + (size_t)te * DIM;
    }
    float4 g0 = *(const float4*)(gp + d0), g1 = *(const float4*)(gp + d0 + 4);
    float4 b0 = *(const float4*)(bp + d0), b1 = *(const float4*)(bp + d0 + 4);
    float gv[8] = { g0.x, g0.y, g0.z, g0.w, g1.x, g1.y, g1.z, g1.w };
    float bv[8] = { b0.x, b0.y, b0.z, b0.w, b1.x, b1.y, b1.z, b1.w };
    float dd = 0;
#pragma unroll
    for (int j = 0; j < 8; j++) {
      float y = (v[j] - mu) * rs * gv[j] + bv[j];
      stv[n][j] = y;
      dd += y * qr[j];
    }
    float* so = stacked + (((size_t)t * 8 + n) * BB + b) * DIM + d0;
    *(float4*)so = *(float4*)&stv[n][0];
    *(float4*)(so + 4) = *(float4*)&stv[n][4];
    dots[n] = wsum(dd);
  }
  float sb = sbias[(size_t)t * BB + b];
  const float inv = 0.04419417382415922f;  // 1/sqrt(512)
  float sc[8], e[8];
  float mx = -1e30f;
#pragma unroll
  for (int n = 0; n < 8; n++) { sc[n] = (dots[n] + sb) * inv; mx = fmaxf(mx, sc[n]); }
  float den = 0;
#pragma unroll
  for (int n = 0; n < 8; n++) { e[n] = expf(sc[n] - mx); den += e[n]; }
  float rden = 1.0f / den;
  float wv[8];
#pragma unroll
  for (int n = 0; n < 8; n++) wv[n] = e[n] * rden;
  float wsel = 0;
#pragma unroll
  for (int n = 0; n < 8; n++) wsel = (lane == n) ? wv[n] : wsel;
  if (lane < 8) wout[((size_t)t * BB + b) * 8 + lane] = wsel;
  float g[8];
#pragma unroll
  for (int j = 0; j < 8; j++) {
    float s = 0;
#pragma unroll
    for (int n = 0; n < 8; n++) s += wv[n] * stv[n][j];
    g[j] = s;
  }
  float* go = gated + rowoff;
  *(float4*)(go) = *(float4*)&g[0];
  *(float4*)(go + 4) = *(float4*)&g[4];
}

// ============================ host launcher ==================================
extern "C" void kernel_launch(void* const* d_in, const int* in_sizes, int n_in,
                              void* d_out, int out_size, void* d_ws, size_t ws_size,
                              hipStream_t stream) {
  const float* ti  = (const float*)d_in[0];
  const float* sw1 = (const float*)d_in[1];
  const float* sb1 = (const float*)d_in[2];
  const float* sw2 = (const float*)d_in[3];
  const float* sb2 = (const float*)d_in[4];
  const float* sg  = (const float*)d_in[5];
  const float* sbt = (const float*)d_in[6];
  const float* tw1 = (const float*)d_in[7];
  const float* tb1 = (const float*)d_in[8];
  const float* tw2 = (const float*)d_in[9];
  const float* tb2 = (const float*)d_in[10];
  const float* tg  = (const float*)d_in[11];
  const float* tbt = (const float*)d_in[12];
  const float* qw  = (const float*)d_in[13];
  const float* qb  = (const float*)d_in[14];
  const float* kw  = (const float*)d_in[15];
  const float* kb  = (const float*)d_in[16];

  float* out = (float*)d_out;
  float* gated   = out;                                   // T*B*D
  float* weights = out + (size_t)TT * BB * DIM;           // T*B*8
  float* stacked = weights + (size_t)TT * BB * 8;         // T*8*B*D

  char* ws = (char*)d_ws;
  u16*   tib   = (u16*)(ws);                    // 16,777,216
  u16*   xsb   = (u16*)(ws + 16777216);         //  4,194,304
  u16*   w1t   = (u16*)(ws + 20971520);         // 20,971,520
  u16*   w2t   = (u16*)(ws + 41943040);         // 20,971,520
  u16*   qwb   = (u16*)(ws + 62914560);         //  2,097,152
  u16*   kwb   = (u16*)(ws + 65011712);         //  2,097,152
  u16*   mt    = (u16*)(ws + 67108864);         //  2,097,152
  float* sbias = (float*)(ws + 69206016);       //     65,536
  float* qwkb  = (float*)(ws + 69271552);       //      8,192
  float* kwqb  = (float*)(ws + 69279744);       //      8,192
  float* kbqb  = (float*)(ws + 69287936);       //      1,024
  u16*   qkb   = (u16*)(ws + 69288960);         // 16,777,216
  u16*   stk16 = (u16*)(ws + 86066176);         // 83,886,080 (20*B*D bf16)
  u16*   hbuf  = (u16*)(ws + 169952256);        // SR*HDIM*2*20

  const size_t hoff = 169952256;
  int SR = 512;
  if (ws_size >= hoff + (size_t)NEXP * BB * HDIM * 2) SR = BB;           // 338 MB
  else if (ws_size >= hoff + (size_t)NEXP * 1024 * HDIM * 2) SR = 1024;

  // weight / gate preprocessing
  k_tcast<<<dim3(32, 16, 4), 256, 0, stream>>>(sw1, w1t, DIM, HDIM);
  k_tcast<<<dim3(32, 16, 16), 256, 0, stream>>>(tw1, w1t + (size_t)4 * HDIM * DIM, DIM, HDIM);
  k_tcast<<<dim3(16, 32, 4), 256, 0, stream>>>(sw2, w2t, HDIM, DIM);
  k_tcast<<<dim3(16, 32, 16), 256, 0, stream>>>(tw2, w2t + (size_t)4 * DIM * HDIM, HDIM, DIM);
  k_cast<<<1024, 256, 0, stream>>>(qw, qwb);
  k_cast<<<1024, 256, 0, stream>>>(kw, kwb);
  k_biasvec<<<1025, 256, 0, stream>>>(qw, kb, kw, qb, qwkb, kwqb, kbqb);
  k_prep<<<1024, 256, 0, stream>>>(ti, qwkb, kbqb, tib, xsb, sbias);
  k_gemm_mt<<<dim3(4, 4, 4), 256, 0, stream>>>(kwb, qwb, mt);

  // expert FFNs: 128x128 tiles, BK=32 triple-ring counted-vmcnt pipeline
  for (int row0 = 0; row0 < BB; row0 += SR) {
    k_gemm_up<<<dim3(8, SR / 128, NEXP), 256, 0, stream>>>(xsb, tib, w1t, sb1, tb1,
                                                           hbuf, row0, SR);
    k_gemm_down<<<dim3(4, SR / 128, NEXP), 256, 0, stream>>>(hbuf, w2t, sb2, tb2,
                                                             xsb, tib, stk16, row0, SR);
  }

  k_gemm_qk<<<dim3(4, 32, 4), 256, 0, stream>>>(tib, mt, kwqb, qkb);
  k_score<<<4096, 256, 0, stream>>>(stk16, qkb, sbias, sg, sbt, tg, tbt,
                                    stacked, gated, weights);
}

// Round 15
// 496.953 us; speedup vs baseline: 1.0847x; 1.0391x over previous
//
#include <hip/hip_runtime.h>
#include <math.h>

typedef unsigned short u16;
typedef short short8 __attribute__((ext_vector_type(8)));
typedef float f32x4 __attribute__((ext_vector_type(4)));

#define TT 4
#define BB 4096
#define DIM 512
#define HDIM 1024
#define BD (BB*DIM)      // 2097152
#define D2 (DIM*DIM)     // 262144
#define NEXP 20

#define GLOAD16(gp, lp) __builtin_amdgcn_global_load_lds( \
    (__attribute__((address_space(1))) void*)(void*)(gp), \
    (__attribute__((address_space(3))) void*)(void*)(lp), 16, 0, 0)

__device__ __forceinline__ u16 f2b(float f) {
  union { float f; unsigned u; } x; x.f = f;
  unsigned r = x.u + 0x7FFFu + ((x.u >> 16) & 1u);
  return (u16)(r >> 16);
}
__device__ __forceinline__ float b2f(u16 v) {
  union { unsigned u; float f; } x; x.u = ((unsigned)v) << 16; return x.f;
}

__device__ __forceinline__ float wsum(float v) {
#pragma unroll
  for (int o = 32; o > 0; o >>= 1) v += __shfl_xor(v, o);
  return v;
}

// fast exact-enough GELU
__device__ __forceinline__ float fgelu(float v) {
  float u = 1.5957691216057308f * v * (1.0f + 0.044715f * v * v);
  return v / (1.0f + __expf(-u));
}

// ------ prep: one wave per row b: mean, bf16 casts, score-bias sbias --------
__global__ __launch_bounds__(256) void k_prep(const float* __restrict__ ti,
                                              const float* __restrict__ qwkb,
                                              const float* __restrict__ kbqb,
                                              u16* __restrict__ tib,
                                              u16* __restrict__ xsb,
                                              float* __restrict__ sbias) {
  int gw = (blockIdx.x * 256 + threadIdx.x) >> 6;   // row b
  int lane = threadIdx.x & 63;
  int d0 = lane * 8;
  float x[4][8];
#pragma unroll
  for (int t = 0; t < 4; t++) {
    const float* p = ti + ((size_t)t * BB + gw) * DIM + d0;
    *(float4*)&x[t][0] = *(const float4*)p;
    *(float4*)&x[t][4] = *(const float4*)(p + 4);
  }
  float m[8];
#pragma unroll
  for (int j = 0; j < 8; j++)
    m[j] = (x[0][j] + x[1][j] + x[2][j] + x[3][j]) * 0.25f;
#pragma unroll
  for (int t = 0; t < 4; t++) {
    ushort4 c0 = { f2b(x[t][0]), f2b(x[t][1]), f2b(x[t][2]), f2b(x[t][3]) };
    ushort4 c1 = { f2b(x[t][4]), f2b(x[t][5]), f2b(x[t][6]), f2b(x[t][7]) };
    u16* q = tib + ((size_t)t * BB + gw) * DIM + d0;
    *(ushort4*)q = c0; *(ushort4*)(q + 4) = c1;
  }
  {
    ushort4 c0 = { f2b(m[0]), f2b(m[1]), f2b(m[2]), f2b(m[3]) };
    ushort4 c1 = { f2b(m[4]), f2b(m[5]), f2b(m[6]), f2b(m[7]) };
    u16* q = xsb + (size_t)gw * DIM + d0;
    *(ushort4*)q = c0; *(ushort4*)(q + 4) = c1;
  }
#pragma unroll
  for (int t = 0; t < 4; t++) {
    const float* wp = qwkb + (size_t)t * DIM + d0;
    float4 w0 = *(const float4*)wp, w1 = *(const float4*)(wp + 4);
    float s = x[t][0]*w0.x + x[t][1]*w0.y + x[t][2]*w0.z + x[t][3]*w0.w
            + x[t][4]*w1.x + x[t][5]*w1.y + x[t][6]*w1.z + x[t][7]*w1.w;
    s = wsum(s);
    if (lane == 0) sbias[(size_t)t * BB + gw] = s + kbqb[t];
  }
}

// ------------- batched transpose+cast: (G,R,C) f32 -> (G,C,R) bf16 -----------
__global__ __launch_bounds__(256) void k_tcast(const float* __restrict__ in,
                                               u16* __restrict__ out,
                                               int R, int C) {
  __shared__ float tile[32][33];
  size_t gb = (size_t)blockIdx.z * R * C;
  in += gb; out += gb;
  int c0 = blockIdx.x * 32, r0 = blockIdx.y * 32;
  int tx = threadIdx.x & 31, ty = threadIdx.x >> 5;
#pragma unroll
  for (int j = 0; j < 4; j++)
    tile[ty + j * 8][tx] = in[(size_t)(r0 + ty + j * 8) * C + c0 + tx];
  __syncthreads();
#pragma unroll
  for (int j = 0; j < 4; j++)
    out[(size_t)(c0 + ty + j * 8) * R + r0 + tx] = f2b(tile[tx][ty + j * 8]);
}

// ---------------- plain cast f32 -> bf16 -------------------------------------
__global__ __launch_bounds__(256) void k_cast(const float* __restrict__ in,
                                              u16* __restrict__ out) {
  size_t i = ((size_t)blockIdx.x * 256 + threadIdx.x) * 4;
  float4 v = *(const float4*)(in + i);
  ushort4 b = { f2b(v.x), f2b(v.y), f2b(v.z), f2b(v.w) };
  *(ushort4*)(out + i) = b;
}

// --------------- small bias-vector precomputes -------------------------------
__global__ __launch_bounds__(256) void k_biasvec(const float* __restrict__ qw,
                                                 const float* __restrict__ kb,
                                                 const float* __restrict__ kw,
                                                 const float* __restrict__ qb,
                                                 float* __restrict__ qwkb,
                                                 float* __restrict__ kwqb,
                                                 float* __restrict__ kbqb) {
  int gw = (blockIdx.x * 256 + threadIdx.x) >> 6;
  int lane = threadIdx.x & 63;
  if (gw < 2048) {
    int t = gw >> 9, c = gw & 511;
    const float* row = qw + ((size_t)t * DIM + c) * DIM;
    const float* v = kb + (size_t)t * DIM;
    float s = 0;
#pragma unroll
    for (int j = 0; j < 8; j++) s += row[lane * 8 + j] * v[lane * 8 + j];
    s = wsum(s);
    if (lane == 0) qwkb[(size_t)t * DIM + c] = s;
  } else if (gw < 4096) {
    int t = (gw - 2048) >> 9, d = gw & 511;
    const float* row = kw + ((size_t)t * DIM + d) * DIM;
    const float* v = qb + (size_t)t * DIM;
    float s = 0;
#pragma unroll
    for (int j = 0; j < 8; j++) s += row[lane * 8 + j] * v[lane * 8 + j];
    s = wsum(s);
    if (lane == 0) kwqb[(size_t)t * DIM + d] = s;
  } else if (gw < 4100) {
    int t = gw - 4096;
    const float* a = kb + (size_t)t * DIM;
    const float* c = qb + (size_t)t * DIM;
    float s = 0;
#pragma unroll
    for (int j = 0; j < 8; j++) s += a[lane * 8 + j] * c[lane * 8 + j];
    s = wsum(s);
    if (lane == 0) kbqb[t] = s;
  }
}

// ---- 256x128 bf16 MFMA GEMM, 512 thr, BK=32, triple-ring counted vmcnt ------
// 85 FLOP/byte staged (vs 64 at 128^2); 72 KB LDS -> 2 blocks/CU.
// Per thread per tile: 3 loads (2 A + 1 B); end-of-iter vmcnt(3) keeps tile
// k+2 in flight across the barrier (never drains in the main loop).
template <bool SWAPPED>
__device__ __forceinline__ void gemmBigr(const u16* __restrict__ Ag, int lda,
                                         const u16* __restrict__ Bg, int ldb,
                                         int K, f32x4 acc[4][4]) {
  __shared__ __align__(16) u16 lA[3][8192];   // 3 x (256 x 32)
  __shared__ __align__(16) u16 lB[3][4096];   // 3 x (128 x 32)
  const int tid = threadIdx.x;                // 0..511
  const int lane = tid & 63;
  const int wave = tid >> 6;                  // 0..7
  const int wm = wave >> 1, wn = wave & 1;    // 4 x 2 wave grid, 64x64 tiles
  const int rl = lane & 15;
  const int row = tid >> 2;                   // 0..127
  const int gc = ((tid & 3) ^ ((row >> 1) & 3)) * 8;    // pre-swizzled chunk
  const int hs = (((lane >> 4) ^ ((rl >> 1) & 3))) * 8; // swizzled read chunk
  const u16* a0 = Ag + (size_t)row * lda + gc;          // A rows 0..127
  const u16* a1 = a0 + (size_t)128 * lda;               // A rows 128..255
  const u16* b0 = Bg + (size_t)row * ldb + gc;          // B rows 0..127
  const int ao = (wm * 64 + rl) * 32 + hs;    // + mf*512 (swizzle inv. mod 16)
  const int bo = (wn * 64 + rl) * 32 + hs;    // + nf*512
  const int nst = K >> 5;
  // prologue: stage tiles 0 and 1
  GLOAD16(a0, &lA[0][tid * 8]);
  GLOAD16(a1, &lA[0][4096 + tid * 8]);
  GLOAD16(b0, &lB[0][tid * 8]);
  GLOAD16(a0 + 32, &lA[1][tid * 8]);
  GLOAD16(a1 + 32, &lA[1][4096 + tid * 8]);
  GLOAD16(b0 + 32, &lB[1][tid * 8]);
  asm volatile("s_waitcnt vmcnt(3)" ::: "memory");  // tile0 landed
  __builtin_amdgcn_s_barrier();
  __builtin_amdgcn_sched_barrier(0);
  for (int k = 0; k < nst; ++k) {
    const int cur = k % 3;
    if (k + 2 < nst) {                   // issue tile k+2 into ring slot
      const int off = (k + 2) * 32;
      const int nb = (k + 2) % 3;
      GLOAD16(a0 + off, &lA[nb][tid * 8]);
      GLOAD16(a1 + off, &lA[nb][4096 + tid * 8]);
      GLOAD16(b0 + off, &lB[nb][tid * 8]);
    }
    short8 af[4], bf[4];
#pragma unroll
    for (int i = 0; i < 4; i++) {
      af[i] = *(const short8*)&lA[cur][ao + i * 512];
      bf[i] = *(const short8*)&lB[cur][bo + i * 512];
    }
    __builtin_amdgcn_s_setprio(1);
    if (SWAPPED) {
#pragma unroll
      for (int mi = 0; mi < 4; mi++)
#pragma unroll
        for (int ni = 0; ni < 4; ni++)
          acc[mi][ni] = __builtin_amdgcn_mfma_f32_16x16x32_bf16(bf[ni], af[mi],
                                                                acc[mi][ni], 0, 0, 0);
    } else {
#pragma unroll
      for (int mi = 0; mi < 4; mi++)
#pragma unroll
        for (int ni = 0; ni < 4; ni++)
          acc[mi][ni] = __builtin_amdgcn_mfma_f32_16x16x32_bf16(af[mi], bf[ni],
                                                                acc[mi][ni], 0, 0, 0);
    }
    __builtin_amdgcn_s_setprio(0);
    // counted wait: tile k+1 landed; tile k+2 (3 loads) stays in flight
    if (k + 2 < nst) asm volatile("s_waitcnt vmcnt(3)" ::: "memory");
    else             asm volatile("s_waitcnt vmcnt(0)" ::: "memory");
    __builtin_amdgcn_s_barrier();
    __builtin_amdgcn_sched_barrier(0);
  }
}

// ---------------- expert up-GEMM: h = gelu(x@W1 + b1), bf16 out --------------
// 256x128 tile, non-swapped epilogue: row=(lane>>4)*4+r, col=lane&15.
__global__ __launch_bounds__(512, 4) void k_gemm_up(const u16* __restrict__ xsb,
                                                 const u16* __restrict__ tib,
                                                 const u16* __restrict__ w1t,
                                                 const float* __restrict__ sb1,
                                                 const float* __restrict__ tb1,
                                                 u16* __restrict__ hbuf,
                                                 int row0, int SR) {
  int ge = blockIdx.z;
  const u16* A;
  const float* bias;
  if (ge < 4) { A = xsb; bias = sb1 + (size_t)ge * HDIM; }
  else {
    int te = ge - 4;
    A = tib + (size_t)(te >> 2) * BD;
    bias = tb1 + (size_t)te * HDIM;
  }
  A += (size_t)row0 * DIM;
  const u16* W = w1t + (size_t)ge * ((size_t)HDIM * DIM);
  int m0 = blockIdx.y * 256, n0 = blockIdx.x * 128;
  f32x4 acc[4][4] = {};
  gemmBigr<false>(A + (size_t)m0 * DIM, DIM, W + (size_t)n0 * DIM, DIM, DIM, acc);
  u16* out = hbuf + (size_t)ge * ((size_t)SR * HDIM);
  const int lane = threadIdx.x & 63, wave = threadIdx.x >> 6;
  const int rbase = m0 + (wave >> 1) * 64 + (lane >> 4) * 4;
  const int cbase = n0 + (wave & 1) * 64 + (lane & 15);
#pragma unroll
  for (int mi = 0; mi < 4; mi++)
#pragma unroll
    for (int ni = 0; ni < 4; ni++)
#pragma unroll
      for (int r = 0; r < 4; r++) {
        int row = rbase + mi * 16 + r;
        int col = cbase + ni * 16;
        float v = acc[mi][ni][r] + bias[col];
        out[(size_t)row * HDIM + col] = f2b(fgelu(v));
      }
}

// ---- down-GEMM: preLN bf16 = h@W2 + b2 + residual -> stk16[20][B][D] --------
// 256x128 tile, swapped epilogue: lane owns (row=rl, 4 cols) -> ushort4.
__global__ __launch_bounds__(512, 4) void k_gemm_down(const u16* __restrict__ hbuf,
                                                   const u16* __restrict__ w2t,
                                                   const float* __restrict__ sb2,
                                                   const float* __restrict__ tb2,
                                                   const u16* __restrict__ xsb,
                                                   const u16* __restrict__ tib,
                                                   u16* __restrict__ stk16,
                                                   int row0, int SR) {
  int ge = blockIdx.z;
  int m0 = blockIdx.y * 256, n0 = blockIdx.x * 128;
  const u16* Ag = hbuf + (size_t)ge * ((size_t)SR * HDIM) + (size_t)m0 * HDIM;
  const u16* Bg = w2t + (size_t)ge * ((size_t)DIM * HDIM) + (size_t)n0 * HDIM;
  f32x4 acc[4][4] = {};
  gemmBigr<true>(Ag, HDIM, Bg, HDIM, HDIM, acc);
  const float* bias; const u16* resb;
  int te = ge - 4;
  if (ge < 4) { bias = sb2 + (size_t)ge * DIM; resb = xsb; }
  else { bias = tb2 + (size_t)te * DIM; resb = tib + (size_t)(te >> 2) * BD; }
  const int lane = threadIdx.x & 63, wave = threadIdx.x >> 6;
  const int rl = lane & 15, c4 = (lane >> 4) * 4;
  const int wm = wave >> 1, wn = wave & 1;
  u16* outb = stk16 + (size_t)ge * BD;
#pragma unroll
  for (int mf = 0; mf < 4; mf++) {
    int grow = row0 + m0 + wm * 64 + mf * 16 + rl;
#pragma unroll
    for (int nf = 0; nf < 4; nf++) {
      int col0 = n0 + wn * 64 + nf * 16 + c4;
      float4 bb = *(const float4*)(bias + col0);
      ushort4 rr = *(const ushort4*)(resb + (size_t)grow * DIM + col0);
      ushort4 y;
      y.x = f2b(acc[mf][nf][0] + bb.x + b2f(rr.x));
      y.y = f2b(acc[mf][nf][1] + bb.y + b2f(rr.y));
      y.z = f2b(acc[mf][nf][2] + bb.z + b2f(rr.z));
      y.w = f2b(acc[mf][nf][3] + bb.w + b2f(rr.w));
      *(ushort4*)(outb + (size_t)grow * DIM + col0) = y;
    }
  }
}

// ---- 128x128 bf16 MFMA GEMM, BK=32, triple-ring (small GEMMs: mt, qk) -------
template <bool SWAPPED>
__device__ __forceinline__ void gemm128r(const u16* __restrict__ Ag, int lda,
                                         const u16* __restrict__ Bg, int ldb,
                                         int K, f32x4 acc[4][4]) {
  __shared__ __align__(16) u16 lA[3][4096];
  __shared__ __align__(16) u16 lB[3][4096];
  const int tid = threadIdx.x;
  const int lane = tid & 63;
  const int wave = tid >> 6;
  const int wm = wave >> 1, wn = wave & 1;
  const int rl = lane & 15;
  const int gc = ((tid & 3) ^ ((tid >> 3) & 3)) * 8;
  const int hs = ((lane >> 4) ^ ((rl >> 1) & 3)) * 8;
  const u16* a0 = Ag + (size_t)(tid >> 2) * lda + gc;
  const u16* a1 = a0 + (size_t)64 * lda;
  const u16* b0 = Bg + (size_t)(tid >> 2) * ldb + gc;
  const u16* b1 = b0 + (size_t)64 * ldb;
  const int ao = (wm * 64 + rl) * 32 + hs;
  const int bo = (wn * 64 + rl) * 32 + hs;
  const int nst = K >> 5;
  GLOAD16(a0, &lA[0][tid * 8]);
  GLOAD16(a1, &lA[0][2048 + tid * 8]);
  GLOAD16(b0, &lB[0][tid * 8]);
  GLOAD16(b1, &lB[0][2048 + tid * 8]);
  GLOAD16(a0 + 32, &lA[1][tid * 8]);
  GLOAD16(a1 + 32, &lA[1][2048 + tid * 8]);
  GLOAD16(b0 + 32, &lB[1][tid * 8]);
  GLOAD16(b1 + 32, &lB[1][2048 + tid * 8]);
  asm volatile("s_waitcnt vmcnt(4)" ::: "memory");
  __builtin_amdgcn_s_barrier();
  __builtin_amdgcn_sched_barrier(0);
  for (int k = 0; k < nst; ++k) {
    const int cur = k % 3;
    if (k + 2 < nst) {
      const int off = (k + 2) * 32;
      const int nb = (k + 2) % 3;
      GLOAD16(a0 + off, &lA[nb][tid * 8]);
      GLOAD16(a1 + off, &lA[nb][2048 + tid * 8]);
      GLOAD16(b0 + off, &lB[nb][tid * 8]);
      GLOAD16(b1 + off, &lB[nb][2048 + tid * 8]);
    }
    short8 af[4], bf[4];
#pragma unroll
    for (int i = 0; i < 4; i++) {
      af[i] = *(const short8*)&lA[cur][ao + i * 512];
      bf[i] = *(const short8*)&lB[cur][bo + i * 512];
    }
    __builtin_amdgcn_s_setprio(1);
    if (SWAPPED) {
#pragma unroll
      for (int mi = 0; mi < 4; mi++)
#pragma unroll
        for (int ni = 0; ni < 4; ni++)
          acc[mi][ni] = __builtin_amdgcn_mfma_f32_16x16x32_bf16(bf[ni], af[mi],
                                                                acc[mi][ni], 0, 0, 0);
    } else {
#pragma unroll
      for (int mi = 0; mi < 4; mi++)
#pragma unroll
        for (int ni = 0; ni < 4; ni++)
          acc[mi][ni] = __builtin_amdgcn_mfma_f32_16x16x32_bf16(af[mi], bf[ni],
                                                                acc[mi][ni], 0, 0, 0);
    }
    __builtin_amdgcn_s_setprio(0);
    if (k + 2 < nst) asm volatile("s_waitcnt vmcnt(4)" ::: "memory");
    else             asm volatile("s_waitcnt vmcnt(0)" ::: "memory");
    __builtin_amdgcn_s_barrier();
    __builtin_amdgcn_sched_barrier(0);
  }
}

// ---------------- MT[t] = kw[t] @ qw[t]^T  (bf16 out) ------------------------
__global__ __launch_bounds__(256) void k_gemm_mt(const u16* __restrict__ kwb,
                                                 const u16* __restrict__ qwb,
                                                 u16* __restrict__ mt) {
  int t = blockIdx.z;
  int m0 = blockIdx.y * 128, n0 = blockIdx.x * 128;
  f32x4 acc[4][4] = {};
  gemm128r<true>(kwb + (size_t)t * D2 + (size_t)m0 * DIM, DIM,
                 qwb + (size_t)t * D2 + (size_t)n0 * DIM, DIM, DIM, acc);
  const int lane = threadIdx.x & 63, wave = threadIdx.x >> 6;
  const int rl = lane & 15, c4 = (lane >> 4) * 4;
  const int wm = wave >> 1, wn = wave & 1;
#pragma unroll
  for (int mf = 0; mf < 4; mf++) {
    int row = m0 + wm * 64 + mf * 16 + rl;
#pragma unroll
    for (int nf = 0; nf < 4; nf++) {
      int col0 = n0 + wn * 64 + nf * 16 + c4;
      ushort4 y = { f2b(acc[mf][nf][0]), f2b(acc[mf][nf][1]),
                    f2b(acc[mf][nf][2]), f2b(acc[mf][nf][3]) };
      *(ushort4*)(mt + (size_t)t * D2 + (size_t)row * DIM + col0) = y;
    }
  }
}

// ------------- qkb[t] = bf16(x[t] @ MT[t]^T + kwqb[t]) -----------------------
__global__ __launch_bounds__(256) void k_gemm_qk(const u16* __restrict__ tib,
                                                 const u16* __restrict__ mt,
                                                 const float* __restrict__ kwqb,
                                                 u16* __restrict__ qkb) {
  int t = blockIdx.z;
  int m0 = blockIdx.y * 128, n0 = blockIdx.x * 128;
  f32x4 acc[4][4] = {};
  gemm128r<true>(tib + (size_t)t * BD + (size_t)m0 * DIM, DIM,
                 mt + (size_t)t * D2 + (size_t)n0 * DIM, DIM, DIM, acc);
  const int lane = threadIdx.x & 63, wave = threadIdx.x >> 6;
  const int rl = lane & 15, c4 = (lane >> 4) * 4;
  const int wm = wave >> 1, wn = wave & 1;
#pragma unroll
  for (int mf = 0; mf < 4; mf++) {
    int row = m0 + wm * 64 + mf * 16 + rl;
#pragma unroll
    for (int nf = 0; nf < 4; nf++) {
      int col0 = n0 + wn * 64 + nf * 16 + c4;
      float4 bb = *(const float4*)(kwqb + (size_t)t * DIM + col0);
      ushort4 y;
      y.x = f2b(acc[mf][nf][0] + bb.x);
      y.y = f2b(acc[mf][nf][1] + bb.y);
      y.z = f2b(acc[mf][nf][2] + bb.z);
      y.w = f2b(acc[mf][nf][3] + bb.w);
      *(ushort4*)(qkb + (size_t)t * BD + (size_t)row * DIM + col0) = y;
    }
  }
}

// ---- fused LN + scores + softmax + gating (one wave per (t,b)) --------------
__global__ __launch_bounds__(256) void k_score(const u16* __restrict__ stk16,
                                               const u16* __restrict__ qkb,
                                               const float* __restrict__ sbias,
                                               const float* __restrict__ sg,
                                               const float* __restrict__ sbt,
                                               const float* __restrict__ tg,
                                               const float* __restrict__ tbt,
                                               float* __restrict__ stacked,
                                               float* __restrict__ gated,
                                               float* __restrict__ wout) {
  int gw = (blockIdx.x * 256 + threadIdx.x) >> 6;
  int lane = threadIdx.x & 63;
  int b = gw & (BB - 1), t = gw >> 12;
  int d0 = lane * 8;
  size_t rowoff = ((size_t)t * BB + b) * DIM + d0;
  float qr[8];
  {
    ushort4 q0 = *(const ushort4*)(qkb + rowoff);
    ushort4 q1 = *(const ushort4*)(qkb + rowoff + 4);
    qr[0] = b2f(q0.x); qr[1] = b2f(q0.y); qr[2] = b2f(q0.z); qr[3] = b2f(q0.w);
    qr[4] = b2f(q1.x); qr[5] = b2f(q1.y); qr[6] = b2f(q1.z); qr[7] = b2f(q1.w);
  }
  float stv[8][8];
  float dots[8];
#pragma unroll
  for (int n = 0; n < 8; n++) {
    int e = (n < 4) ? n : (4 + t * 4 + (n - 4));
    const u16* sp = stk16 + ((size_t)e * BB + b) * DIM + d0;
    ushort4 v0 = *(const ushort4*)sp;
    ushort4 v1 = *(const ushort4*)(sp + 4);
    float v[8] = { b2f(v0.x), b2f(v0.y), b2f(v0.z), b2f(v0.w),
                   b2f(v1.x), b2f(v1.y), b2f(v1.z), b2f(v1.w) };
    float S = 0, Q = 0;
#pragma unroll
    for (int j = 0; j < 8; j++) { S += v[j]; Q += v[j] * v[j]; }
    S = wsum(S); Q = wsum(Q);
    float mu = S * (1.0f / DIM);
    float var = Q * (1.0f / DIM) - mu * mu;
    float rs = rsqrtf(var + 1e-5f);
    const float* gp; const float* bp;
    if (n < 4) { gp = sg + (size_t)n * DIM; bp = sbt + (size_t)n * DIM; }
    else {
      int te = t * 4 + (n - 4);
      gp = tg + (size_t)te * DIM; bp = tbt + (size_t)te * DIM;
    }
    float4 g0 = *(const float4*)(gp + d0), g1 = *(const float4*)(gp + d0 + 4);
    float4 b0 = *(const float4*)(bp + d0), b1 = *(const float4*)(bp + d0 + 4);
    float gv[8] = { g0.x, g0.y, g0.z, g0.w, g1.x, g1.y, g1.z, g1.w };
    float bv[8] = { b0.x, b0.y, b0.z, b0.w, b1.x, b1.y, b1.z, b1.w };
    float dd = 0;
#pragma unroll
    for (int j = 0; j < 8; j++) {
      float y = (v[j] - mu) * rs * gv[j] + bv[j];
      stv[n][j] = y;
      dd += y * qr[j];
    }
    float* so = stacked + (((size_t)t * 8 + n) * BB + b) * DIM + d0;
    *(float4*)so = *(float4*)&stv[n][0];
    *(float4*)(so + 4) = *(float4*)&stv[n][4];
    dots[n] = wsum(dd);
  }
  float sb = sbias[(size_t)t * BB + b];
  const float inv = 0.04419417382415922f;  // 1/sqrt(512)
  float sc[8], e[8];
  float mx = -1e30f;
#pragma unroll
  for (int n = 0; n < 8; n++) { sc[n] = (dots[n] + sb) * inv; mx = fmaxf(mx, sc[n]); }
  float den = 0;
#pragma unroll
  for (int n = 0; n < 8; n++) { e[n] = expf(sc[n] - mx); den += e[n]; }
  float rden = 1.0f / den;
  float wv[8];
#pragma unroll
  for (int n = 0; n < 8; n++) wv[n] = e[n] * rden;
  float wsel = 0;
#pragma unroll
  for (int n = 0; n < 8; n++) wsel = (lane == n) ? wv[n] : wsel;
  if (lane < 8) wout[((size_t)t * BB + b) * 8 + lane] = wsel;
  float g[8];
#pragma unroll
  for (int j = 0; j < 8; j++) {
    float s = 0;
#pragma unroll
    for (int n = 0; n < 8; n++) s += wv[n] * stv[n][j];
    g[j] = s;
  }
  float* go = gated + rowoff;
  *(float4*)(go) = *(float4*)&g[0];
  *(float4*)(go + 4) = *(float4*)&g[4];
}

// ============================ host launcher ==================================
extern "C" void kernel_launch(void* const* d_in, const int* in_sizes, int n_in,
                              void* d_out, int out_size, void* d_ws, size_t ws_size,
                              hipStream_t stream) {
  const float* ti  = (const float*)d_in[0];
  const float* sw1 = (const float*)d_in[1];
  const float* sb1 = (const float*)d_in[2];
  const float* sw2 = (const float*)d_in[3];
  const float* sb2 = (const float*)d_in[4];
  const float* sg  = (const float*)d_in[5];
  const float* sbt = (const float*)d_in[6];
  const float* tw1 = (const float*)d_in[7];
  const float* tb1 = (const float*)d_in[8];
  const float* tw2 = (const float*)d_in[9];
  const float* tb2 = (const float*)d_in[10];
  const float* tg  = (const float*)d_in[11];
  const float* tbt = (const float*)d_in[12];
  const float* qw  = (const float*)d_in[13];
  const float* qb  = (const float*)d_in[14];
  const float* kw  = (const float*)d_in[15];
  const float* kb  = (const float*)d_in[16];

  float* out = (float*)d_out;
  float* gated   = out;                                   // T*B*D
  float* weights = out + (size_t)TT * BB * DIM;           // T*B*8
  float* stacked = weights + (size_t)TT * BB * 8;         // T*8*B*D

  char* ws = (char*)d_ws;
  u16*   tib   = (u16*)(ws);                    // 16,777,216
  u16*   xsb   = (u16*)(ws + 16777216);         //  4,194,304
  u16*   w1t   = (u16*)(ws + 20971520);         // 20,971,520
  u16*   w2t   = (u16*)(ws + 41943040);         // 20,971,520
  u16*   qwb   = (u16*)(ws + 62914560);         //  2,097,152
  u16*   kwb   = (u16*)(ws + 65011712);         //  2,097,152
  u16*   mt    = (u16*)(ws + 67108864);         //  2,097,152
  float* sbias = (float*)(ws + 69206016);       //     65,536
  float* qwkb  = (float*)(ws + 69271552);       //      8,192
  float* kwqb  = (float*)(ws + 69279744);       //      8,192
  float* kbqb  = (float*)(ws + 69287936);       //      1,024
  u16*   qkb   = (u16*)(ws + 69288960);         // 16,777,216
  u16*   stk16 = (u16*)(ws + 86066176);         // 83,886,080 (20*B*D bf16)
  u16*   hbuf  = (u16*)(ws + 169952256);        // SR*HDIM*2*20

  const size_t hoff = 169952256;
  int SR = 512;
  if (ws_size >= hoff + (size_t)NEXP * BB * HDIM * 2) SR = BB;           // 338 MB
  else if (ws_size >= hoff + (size_t)NEXP * 1024 * HDIM * 2) SR = 1024;

  // weight / gate preprocessing
  k_tcast<<<dim3(32, 16, 4), 256, 0, stream>>>(sw1, w1t, DIM, HDIM);
  k_tcast<<<dim3(32, 16, 16), 256, 0, stream>>>(tw1, w1t + (size_t)4 * HDIM * DIM, DIM, HDIM);
  k_tcast<<<dim3(16, 32, 4), 256, 0, stream>>>(sw2, w2t, HDIM, DIM);
  k_tcast<<<dim3(16, 32, 16), 256, 0, stream>>>(tw2, w2t + (size_t)4 * DIM * HDIM, HDIM, DIM);
  k_cast<<<1024, 256, 0, stream>>>(qw, qwb);
  k_cast<<<1024, 256, 0, stream>>>(kw, kwb);
  k_biasvec<<<1025, 256, 0, stream>>>(qw, kb, kw, qb, qwkb, kwqb, kbqb);
  k_prep<<<1024, 256, 0, stream>>>(ti, qwkb, kbqb, tib, xsb, sbias);
  k_gemm_mt<<<dim3(4, 4, 4), 256, 0, stream>>>(kwb, qwb, mt);

  // expert FFNs: 256x128 tiles, BK=32 triple-ring counted-vmcnt pipeline
  for (int row0 = 0; row0 < BB; row0 += SR) {
    k_gemm_up<<<dim3(8, SR / 256, NEXP), 512, 0, stream>>>(xsb, tib, w1t, sb1, tb1,
                                                           hbuf, row0, SR);
    k_gemm_down<<<dim3(4, SR / 256, NEXP), 512, 0, stream>>>(hbuf, w2t, sb2, tb2,
                                                             xsb, tib, stk16, row0, SR);
  }

  k_gemm_qk<<<dim3(4, 32, 4), 256, 0, stream>>>(tib, mt, kwqb, qkb);
  k_score<<<4096, 256, 0, stream>>>(stk16, qkb, sbias, sg, sbt, tg, tbt,
                                    stacked, gated, weights);
}